// Round 1
// 3006.167 us; speedup vs baseline: 1.6321x; 1.6321x over previous
//
#include <hip/hip_runtime.h>
#include <hip/hip_bf16.h>

#define D_ 1024
#define S_ 1024
#define B_ 2
#define H_ 16
#define F_ 4096
#define L_ 6

typedef __bf16 bf16x8 __attribute__((ext_vector_type(8)));
typedef float f32x4 __attribute__((ext_vector_type(4)));

__device__ __forceinline__ unsigned short f2bf(float f){
  union { float f; unsigned u; } v; v.f = f;
  unsigned r = v.u + 0x7fffu + ((v.u >> 16) & 1u);
  return (unsigned short)(r >> 16);
}
__device__ __forceinline__ uint pk2(float lo, float hi){
  return (uint)f2bf(lo) | ((uint)f2bf(hi) << 16);
}
__device__ __forceinline__ uint4 pack8(float4 a, float4 b){
  uint4 r; r.x = pk2(a.x,a.y); r.y = pk2(a.z,a.w); r.z = pk2(b.x,b.y); r.w = pk2(b.z,b.w); return r;
}

// ---------------- embedding ----------------
__global__ void k_embed(const int* __restrict__ ids, const float* __restrict__ tok,
                        const float* __restrict__ pos, float* __restrict__ x){
  int row = blockIdx.x;            // b*S + s
  int s = row & (S_-1);
  int id = ids[row];
  int t = threadIdx.x;
  float4 te = ((const float4*)(tok + (size_t)id*D_))[t];
  float4 pe = ((const float4*)(pos + (size_t)s*D_))[t];
  float4 o; o.x=te.x+pe.x; o.y=te.y+pe.y; o.z=te.z+pe.z; o.w=te.w+pe.w;
  ((float4*)(x + (size_t)row*D_))[t] = o;
}

// ---------------- layernorm -> bf16 ----------------
__global__ void k_ln(const float* __restrict__ x, const float* __restrict__ g,
                     const float* __restrict__ b, ushort* __restrict__ h){
  int row = blockIdx.x;
  int t = threadIdx.x;
  float4 v = ((const float4*)(x + (size_t)row*D_))[t];
  float s1 = v.x+v.y+v.z+v.w;
  float s2 = v.x*v.x+v.y*v.y+v.z*v.z+v.w*v.w;
  #pragma unroll
  for (int o=1;o<64;o<<=1){ s1 += __shfl_xor(s1,o); s2 += __shfl_xor(s2,o); }
  __shared__ float sm[8];
  int w = t>>6;
  if ((t&63)==0){ sm[w]=s1; sm[4+w]=s2; }
  __syncthreads();
  s1 = sm[0]+sm[1]+sm[2]+sm[3];
  s2 = sm[4]+sm[5]+sm[6]+sm[7];
  float mu = s1 * (1.0f/D_);
  float var = s2 * (1.0f/D_) - mu*mu;
  float rs = rsqrtf(var + 1e-5f);
  float4 gv = ((const float4*)g)[t];
  float4 bv = ((const float4*)b)[t];
  union { ushort u[4]; uint2 p; } o;
  o.u[0] = f2bf((v.x-mu)*rs*gv.x + bv.x);
  o.u[1] = f2bf((v.y-mu)*rs*gv.y + bv.y);
  o.u[2] = f2bf((v.z-mu)*rs*gv.z + bv.z);
  o.u[3] = f2bf((v.w-mu)*rs*gv.w + bv.w);
  ((uint2*)(h + (size_t)row*D_))[t] = o.p;
}

// ---------------- final layernorm (last token per batch) -> fp32 out ----------------
__global__ void k_lnf(const float* __restrict__ x, const float* __restrict__ g,
                      const float* __restrict__ b, float* __restrict__ out){
  int row = blockIdx.x*S_ + (S_-1);
  int t = threadIdx.x;
  float4 v = ((const float4*)(x + (size_t)row*D_))[t];
  float s1 = v.x+v.y+v.z+v.w;
  float s2 = v.x*v.x+v.y*v.y+v.z*v.z+v.w*v.w;
  #pragma unroll
  for (int o=1;o<64;o<<=1){ s1 += __shfl_xor(s1,o); s2 += __shfl_xor(s2,o); }
  __shared__ float sm[8];
  int w = t>>6;
  if ((t&63)==0){ sm[w]=s1; sm[4+w]=s2; }
  __syncthreads();
  s1 = sm[0]+sm[1]+sm[2]+sm[3];
  s2 = sm[4]+sm[5]+sm[6]+sm[7];
  float mu = s1 * (1.0f/D_);
  float var = s2 * (1.0f/D_) - mu*mu;
  float rs = rsqrtf(var + 1e-5f);
  float4 gv = ((const float4*)g)[t];
  float4 bv = ((const float4*)b)[t];
  float4 y;
  y.x = (v.x-mu)*rs*gv.x + bv.x;
  y.y = (v.y-mu)*rs*gv.y + bv.y;
  y.z = (v.z-mu)*rs*gv.z + bv.z;
  y.w = (v.w-mu)*rs*gv.w + bv.w;
  ((float4*)(out + (size_t)blockIdx.x*D_))[t] = y;
}

// ---------------- GEMM: C[m,n] (+)= sum_k A_bf16[m,k] * B_f32[n,k] ----------------
// BM=BN=128, BK=32, 256 threads (4 waves, 2x2), each wave 64x64 via 4x4 MFMA 16x16x32.
// blockIdx.z selects among up to 3 (B,C) pairs (fused QKV / W1W3 launches).
#define LDA 40   // ushort stride: 80B rows -> 16B aligned, ~2-way banks on b128 reads
template<int OP>  // 0: C = acc, 1: C += acc (residual)
__global__ __launch_bounds__(256) void k_gemm_bt(
    const ushort* __restrict__ A,
    const float* __restrict__ B0, const float* __restrict__ B1, const float* __restrict__ B2,
    float* __restrict__ C0, float* __restrict__ C1, float* __restrict__ C2,
    int N, int K){
  const int z = blockIdx.z;
  const float* B = (z==0) ? B0 : ((z==1) ? B1 : B2);
  float* C = (z==0) ? C0 : ((z==1) ? C1 : C2);
  const int m0 = blockIdx.x*128, n0 = blockIdx.y*128;
  __shared__ ushort As[128*LDA];
  __shared__ ushort Bs[128*LDA];
  const int t = threadIdx.x;
  const int lane = t & 63, w = t >> 6;
  const int wm = (w & 1)*64, wn = (w >> 1)*64;
  const int fr = lane & 15, fk = (lane >> 4)*8;
  const int trow = t >> 1, tcol = (t & 1)*16;
  const ushort* Ag = A + (size_t)(m0 + trow)*K + tcol;
  const float*  Bg = B + (size_t)(n0 + trow)*K + tcol;
  ushort* Asw = &As[trow*LDA + tcol];
  ushort* Bsw = &Bs[trow*LDA + tcol];

  f32x4 acc[4][4];
  #pragma unroll
  for (int i=0;i<4;i++)
    #pragma unroll
    for (int j=0;j<4;j++)
      #pragma unroll
      for (int r=0;r<4;r++) acc[i][j][r] = 0.0f;

  for (int k0 = 0; k0 < K; k0 += 32){
    uint4 a0 = *(const uint4*)(Ag + k0);
    uint4 a1 = *(const uint4*)(Ag + k0 + 8);
    float4 q0 = *(const float4*)(Bg + k0);
    float4 q1 = *(const float4*)(Bg + k0 + 4);
    float4 q2 = *(const float4*)(Bg + k0 + 8);
    float4 q3 = *(const float4*)(Bg + k0 + 12);
    __syncthreads();   // previous iter's frag reads done
    *(uint4*)(Asw)     = a0;
    *(uint4*)(Asw + 8) = a1;
    *(uint4*)(Bsw)     = pack8(q0, q1);
    *(uint4*)(Bsw + 8) = pack8(q2, q3);
    __syncthreads();
    bf16x8 af[4], bfr[4];
    #pragma unroll
    for (int i=0;i<4;i++) af[i]  = *(const bf16x8*)&As[(wm + i*16 + fr)*LDA + fk];
    #pragma unroll
    for (int j=0;j<4;j++) bfr[j] = *(const bf16x8*)&Bs[(wn + j*16 + fr)*LDA + fk];
    #pragma unroll
    for (int i=0;i<4;i++)
      #pragma unroll
      for (int j=0;j<4;j++)
        acc[i][j] = __builtin_amdgcn_mfma_f32_16x16x32_bf16(af[i], bfr[j], acc[i][j], 0, 0, 0);
  }
  // epilogue: C/D layout col=lane&15, row=(lane>>4)*4+reg
  #pragma unroll
  for (int i=0;i<4;i++){
    int row = m0 + wm + i*16 + (lane >> 4)*4;
    #pragma unroll
    for (int j=0;j<4;j++){
      int col = n0 + wn + j*16 + (lane & 15);
      float* cp = C + (size_t)row*N + col;
      #pragma unroll
      for (int r=0;r<4;r++){
        if (OP == 0) cp[(size_t)r*N] = acc[i][j][r];
        else         cp[(size_t)r*N] += acc[i][j][r];
      }
    }
  }
}

// ---------------- RoPE (Q or K) fp32 -> bf16, same [b,s,h,d] layout ----------------
__global__ void k_rope(const float* __restrict__ src, ushort* __restrict__ dst){
  int idx = blockIdx.x*256 + threadIdx.x;
  int d = idx & 63;
  int s = (idx >> 10) & (S_-1);
  float v = src[idx];
  float p = __shfl_xor(v, 32);
  float rot = (d < 32) ? -p : p;
  float inv = expf(-(float)(d & 31) * 0.28782313662f);  // ln(10000)/32
  float sn, cs; sincosf((float)s * inv, &sn, &cs);
  dst[idx] = f2bf(v*cs + rot*sn);
}

// ---------------- V transpose: (b,s,h,d) fp32 -> [bh][d][S] bf16 ----------------
__global__ void k_vt(const float* __restrict__ v, ushort* __restrict__ vt){
  __shared__ float vl[64*68];
  int t = threadIdx.x;
  int s0 = blockIdx.x*64, bh = blockIdx.y;
  int b = bh >> 4, hh = bh & 15;
  int j = t >> 2, off = (t & 3)*16;
  const float* src = v + ((size_t)(b*S_ + s0 + j))*D_ + hh*64 + off;
  float4 r0 = ((const float4*)src)[0];
  float4 r1 = ((const float4*)src)[1];
  float4 r2 = ((const float4*)src)[2];
  float4 r3 = ((const float4*)src)[3];
  *(float4*)&vl[j*68 + off +  0] = r0;
  *(float4*)&vl[j*68 + off +  4] = r1;
  *(float4*)&vl[j*68 + off +  8] = r2;
  *(float4*)&vl[j*68 + off + 12] = r3;
  __syncthreads();
  int d = t >> 2, so = (t & 3)*16;
  ushort* dst = vt + ((size_t)bh*64 + d)*S_ + s0 + so;
  union { ushort u[8]; uint4 q; } o0, o1;
  #pragma unroll
  for (int jj=0; jj<8; jj++) o0.u[jj] = f2bf(vl[(so + jj)*68 + d]);
  #pragma unroll
  for (int jj=0; jj<8; jj++) o1.u[jj] = f2bf(vl[(so + 8 + jj)*68 + d]);
  *(uint4*)dst       = o0.q;
  *(uint4*)(dst + 8) = o1.q;
}

// ---------------- MFMA flash attention (causal, online softmax) -> bf16 ctx -------
// Block: 64 queries of one (b,h), 4 waves x 16 queries. K/V chunks of 64 in LDS.
// Per wave per chunk: 8 MFMA (QK^T) + online softmax (16-lane reduces) + 8 MFMA (PV).
// Fragment layout (verified in k_gemm_bt): A/B row=lane&15, k=(lane>>4)*8;
//                                          C/D col=lane&15, row=(lane>>4)*4+reg.
#define LDK 72   // ushort stride: 144B rows, 16B aligned, GEMM-class bank pattern
__global__ __launch_bounds__(256) void k_flash(
    const ushort* __restrict__ qh, const ushort* __restrict__ kh,
    const ushort* __restrict__ vt, ushort* __restrict__ ctx){
  __shared__ ushort Kl[64*LDK];      // [key][d]
  __shared__ ushort Vl[64*LDK];      // [d][key]
  __shared__ ushort Pl[4][16*LDK];   // per-wave [q][key]
  const int t = threadIdx.x, lane = t & 63, w = t >> 6;
  const int bh = blockIdx.x, b = bh >> 4, hh = bh & 15;
  // balanced causal schedule: blocks i and i+256 sum to a constant 17 chunks
  const int yy = blockIdx.y;
  const int q0 = 64 * ((yy < 8) ? (15 - 2*yy) : (2*yy - 16));
  const int qw = q0 + w*16;
  const int fr = lane & 15, fk = (lane >> 4)*8;
  bf16x8 qf0, qf1;
  {
    const ushort* qp = qh + ((size_t)(b*S_ + qw + fr))*D_ + hh*64;
    qf0 = *(const bf16x8*)(qp + fk);
    qf1 = *(const bf16x8*)(qp + 32 + fk);
  }
  f32x4 o[4];
  float m[4], l[4];
  #pragma unroll
  for (int r=0;r<4;r++){
    m[r] = -1e30f; l[r] = 0.f;
    #pragma unroll
    for (int j=0;j<4;j++) o[j][r] = 0.f;
  }
  const int nch = q0/64 + 1;
  const int sr = t >> 2, soff = (t & 3)*16;
  ushort* Plw = Pl[w];
  const int rbase = qw + (lane >> 4)*4;
  for (int c=0; c<nch; c++){
    const int k0 = c*64;
    __syncthreads();
    {
      const uint4* ks = (const uint4*)(kh + ((size_t)(b*S_ + k0 + sr))*D_ + hh*64 + soff);
      uint4 ka = ks[0], kb2 = ks[1];
      const uint4* vs = (const uint4*)(vt + ((size_t)(bh*64 + sr))*S_ + k0 + soff);
      uint4 va = vs[0], vb2 = vs[1];
      *(uint4*)&Kl[sr*LDK + soff]     = ka;
      *(uint4*)&Kl[sr*LDK + soff + 8] = kb2;
      *(uint4*)&Vl[sr*LDK + soff]     = va;
      *(uint4*)&Vl[sr*LDK + soff + 8] = vb2;
    }
    __syncthreads();
    // S = Q K^T  (16q x 64k per wave)
    f32x4 sc[4];
    #pragma unroll
    for (int j=0;j<4;j++){
      bf16x8 kf0 = *(const bf16x8*)&Kl[(j*16 + fr)*LDK + fk];
      bf16x8 kf1 = *(const bf16x8*)&Kl[(j*16 + fr)*LDK + 32 + fk];
      f32x4 z; z[0]=0.f; z[1]=0.f; z[2]=0.f; z[3]=0.f;
      z = __builtin_amdgcn_mfma_f32_16x16x32_bf16(qf0, kf0, z, 0, 0, 0);
      sc[j] = __builtin_amdgcn_mfma_f32_16x16x32_bf16(qf1, kf1, z, 0, 0, 0);
    }
    // online softmax per query row (rows live in 16-lane groups)
    #pragma unroll
    for (int r=0;r<4;r++){
      const int qrow = rbase + r;
      float mc = -1e30f;
      #pragma unroll
      for (int j=0;j<4;j++){
        float sv = (k0 + j*16 + fr <= qrow) ? sc[j][r]*0.125f : -1e30f;
        sc[j][r] = sv;
        mc = fmaxf(mc, sv);
      }
      #pragma unroll
      for (int ofs=1; ofs<16; ofs<<=1) mc = fmaxf(mc, __shfl_xor(mc, ofs));
      float mn = fmaxf(m[r], mc);
      float al = expf(m[r] - mn);
      float sum = 0.f;
      #pragma unroll
      for (int j=0;j<4;j++){
        float p = expf(sc[j][r] - mn);
        sum += p;
        Plw[(((lane >> 4)*4) + r)*LDK + j*16 + fr] = f2bf(p);
      }
      #pragma unroll
      for (int ofs=1; ofs<16; ofs<<=1) sum += __shfl_xor(sum, ofs);
      l[r] = l[r]*al + sum;
      m[r] = mn;
      #pragma unroll
      for (int j=0;j<4;j++) o[j][r] *= al;
    }
    // O += P V   (P via wave-private LDS bounce to A-fragment layout; no barrier
    // needed: same-wave LDS RAW is ordered by lgkmcnt)
    bf16x8 pa0 = *(const bf16x8*)&Plw[fr*LDK + fk];
    bf16x8 pa1 = *(const bf16x8*)&Plw[fr*LDK + 32 + fk];
    #pragma unroll
    for (int j=0;j<4;j++){
      bf16x8 vf0 = *(const bf16x8*)&Vl[(j*16 + fr)*LDK + fk];
      bf16x8 vf1 = *(const bf16x8*)&Vl[(j*16 + fr)*LDK + 32 + fk];
      o[j] = __builtin_amdgcn_mfma_f32_16x16x32_bf16(pa0, vf0, o[j], 0, 0, 0);
      o[j] = __builtin_amdgcn_mfma_f32_16x16x32_bf16(pa1, vf1, o[j], 0, 0, 0);
    }
  }
  #pragma unroll
  for (int r=0;r<4;r++){
    float rl = 1.0f / l[r];
    ushort* cp = ctx + ((size_t)(b*S_ + rbase + r))*D_ + hh*64 + fr;
    #pragma unroll
    for (int j=0;j<4;j++) cp[j*16] = f2bf(o[j][r] * rl);
  }
}

// ---------------- silu(g1) * g3 -> bf16 ----------------
__global__ void k_silu(const float* __restrict__ g1, const float* __restrict__ g3,
                       ushort* __restrict__ p){
  int idx = blockIdx.x*256 + threadIdx.x;
  float4 a = ((const float4*)g1)[idx];
  float4 b = ((const float4*)g3)[idx];
  union { ushort u[4]; uint2 v; } o;
  o.u[0] = f2bf(a.x / (1.f + expf(-a.x)) * b.x);
  o.u[1] = f2bf(a.y / (1.f + expf(-a.y)) * b.y);
  o.u[2] = f2bf(a.z / (1.f + expf(-a.z)) * b.z);
  o.u[3] = f2bf(a.w / (1.f + expf(-a.w)) * b.w);
  ((uint2*)p)[idx] = o.v;
}

extern "C" void kernel_launch(void* const* d_in, const int* in_sizes, int n_in,
                              void* d_out, int out_size, void* d_ws, size_t ws_size,
                              hipStream_t stream) {
  const int*   ids  = (const int*)  d_in[0];
  const float* tok  = (const float*)d_in[1];
  const float* pos  = (const float*)d_in[2];
  const float* wq   = (const float*)d_in[3];
  const float* wk   = (const float*)d_in[4];
  const float* wv   = (const float*)d_in[5];
  const float* wo   = (const float*)d_in[6];
  const float* w1   = (const float*)d_in[7];
  const float* w2   = (const float*)d_in[8];
  const float* w3   = (const float*)d_in[9];
  const float* ln1g = (const float*)d_in[10];
  const float* ln1b = (const float*)d_in[11];
  const float* ln2g = (const float*)d_in[12];
  const float* ln2b = (const float*)d_in[13];
  const float* lnfg = (const float*)d_in[14];
  const float* lnfb = (const float*)d_in[15];

  char* wsb = (char*)d_ws;
  float*  x  = (float*) (wsb);                               // 8 MB
  ushort* h  = (ushort*)(wsb + (size_t)8*1024*1024);         // 4 MB
  float*  qb = (float*) (wsb + (size_t)12*1024*1024);        // 8 MB
  float*  kb = (float*) (wsb + (size_t)20*1024*1024);        // 8 MB
  float*  vb = (float*) (wsb + (size_t)28*1024*1024);        // 8 MB
  ushort* qh = (ushort*)(wsb + (size_t)36*1024*1024);        // 4 MB bf16 Q (post-RoPE)
  ushort* kh = (ushort*)(wsb + (size_t)40*1024*1024);        // 4 MB bf16 K (post-RoPE)
  ushort* vt = (ushort*)(wsb + (size_t)12*1024*1024);        // 4 MB bf16 V^T, aliases qb (dead after k_rope)
  ushort* cx = (ushort*)(wsb + (size_t)44*1024*1024);        // 4 MB
  float*  g1 = (float*) (wsb + (size_t)48*1024*1024);        // 32 MB
  float*  g3 = (float*) (wsb + (size_t)80*1024*1024);        // 32 MB
  ushort* pb = (ushort*)(wsb + (size_t)112*1024*1024);       // 16 MB -> total 128 MB

  k_embed<<<B_*S_, 256, 0, stream>>>(ids, tok, pos, x);

  for (int l = 0; l < L_; l++){
    size_t od = (size_t)l*D_*D_;
    size_t fd = (size_t)l*F_*D_;
    k_ln<<<B_*S_, 256, 0, stream>>>(x, ln1g + l*D_, ln1b + l*D_, h);
    // fused Q/K/V
    k_gemm_bt<0><<<dim3(16, 8, 3), 256, 0, stream>>>(h, wq + od, wk + od, wv + od,
                                                     qb, kb, vb, D_, D_);
    k_rope<<<(B_*S_*D_)/256, 256, 0, stream>>>(qb, qh);
    k_rope<<<(B_*S_*D_)/256, 256, 0, stream>>>(kb, kh);
    k_vt<<<dim3(S_/64, B_*H_), 256, 0, stream>>>(vb, vt);
    k_flash<<<dim3(B_*H_, S_/64), 256, 0, stream>>>(qh, kh, vt, cx);
    // attn out projection + residual
    k_gemm_bt<1><<<dim3(16, 8, 1), 256, 0, stream>>>(cx, wo + od, nullptr, nullptr,
                                                     x, nullptr, nullptr, D_, D_);
    k_ln<<<B_*S_, 256, 0, stream>>>(x, ln2g + l*D_, ln2b + l*D_, h);
    // fused W1/W3
    k_gemm_bt<0><<<dim3(16, 32, 2), 256, 0, stream>>>(h, w1 + fd, w3 + fd, nullptr,
                                                      g1, g3, nullptr, F_, D_);
    k_silu<<<(B_*S_*F_)/1024, 256, 0, stream>>>(g1, g3, pb);
    // W2 + residual
    k_gemm_bt<1><<<dim3(16, 8, 1), 256, 0, stream>>>(pb, w2 + fd, nullptr, nullptr,
                                                     x, nullptr, nullptr, D_, F_);
  }

  k_lnf<<<B_, 256, 0, stream>>>(x, lnfg, lnfb, (float*)d_out);
}

// Round 2
// 2461.707 us; speedup vs baseline: 1.9931x; 1.2212x over previous
//
#include <hip/hip_runtime.h>
#include <hip/hip_bf16.h>

#define D_ 1024
#define S_ 1024
#define B_ 2
#define H_ 16
#define F_ 4096
#define L_ 6

typedef __bf16 bf16x8 __attribute__((ext_vector_type(8)));
typedef float f32x4 __attribute__((ext_vector_type(4)));

__device__ __forceinline__ unsigned short f2bf(float f){
  union { float f; unsigned u; } v; v.f = f;
  unsigned r = v.u + 0x7fffu + ((v.u >> 16) & 1u);
  return (unsigned short)(r >> 16);
}
__device__ __forceinline__ uint pk2(float lo, float hi){
  return (uint)f2bf(lo) | ((uint)f2bf(hi) << 16);
}
__device__ __forceinline__ uint4 pack8(float4 a, float4 b){
  uint4 r; r.x = pk2(a.x,a.y); r.y = pk2(a.z,a.w); r.z = pk2(b.x,b.y); r.w = pk2(b.z,b.w); return r;
}

// ---------------- embedding ----------------
__global__ void k_embed(const int* __restrict__ ids, const float* __restrict__ tok,
                        const float* __restrict__ pos, float* __restrict__ x){
  int row = blockIdx.x;            // b*S + s
  int s = row & (S_-1);
  int id = ids[row];
  int t = threadIdx.x;
  float4 te = ((const float4*)(tok + (size_t)id*D_))[t];
  float4 pe = ((const float4*)(pos + (size_t)s*D_))[t];
  float4 o; o.x=te.x+pe.x; o.y=te.y+pe.y; o.z=te.z+pe.z; o.w=te.w+pe.w;
  ((float4*)(x + (size_t)row*D_))[t] = o;
}

// ---------------- layernorm -> bf16 ----------------
__global__ void k_ln(const float* __restrict__ x, const float* __restrict__ g,
                     const float* __restrict__ b, ushort* __restrict__ h){
  int row = blockIdx.x;
  int t = threadIdx.x;
  float4 v = ((const float4*)(x + (size_t)row*D_))[t];
  float s1 = v.x+v.y+v.z+v.w;
  float s2 = v.x*v.x+v.y*v.y+v.z*v.z+v.w*v.w;
  #pragma unroll
  for (int o=1;o<64;o<<=1){ s1 += __shfl_xor(s1,o); s2 += __shfl_xor(s2,o); }
  __shared__ float sm[8];
  int w = t>>6;
  if ((t&63)==0){ sm[w]=s1; sm[4+w]=s2; }
  __syncthreads();
  s1 = sm[0]+sm[1]+sm[2]+sm[3];
  s2 = sm[4]+sm[5]+sm[6]+sm[7];
  float mu = s1 * (1.0f/D_);
  float var = s2 * (1.0f/D_) - mu*mu;
  float rs = rsqrtf(var + 1e-5f);
  float4 gv = ((const float4*)g)[t];
  float4 bv = ((const float4*)b)[t];
  union { ushort u[4]; uint2 p; } o;
  o.u[0] = f2bf((v.x-mu)*rs*gv.x + bv.x);
  o.u[1] = f2bf((v.y-mu)*rs*gv.y + bv.y);
  o.u[2] = f2bf((v.z-mu)*rs*gv.z + bv.z);
  o.u[3] = f2bf((v.w-mu)*rs*gv.w + bv.w);
  ((uint2*)(h + (size_t)row*D_))[t] = o.p;
}

// ---------------- final layernorm (last token per batch) -> fp32 out ----------------
__global__ void k_lnf(const float* __restrict__ x, const float* __restrict__ g,
                      const float* __restrict__ b, float* __restrict__ out){
  int row = blockIdx.x*S_ + (S_-1);
  int t = threadIdx.x;
  float4 v = ((const float4*)(x + (size_t)row*D_))[t];
  float s1 = v.x+v.y+v.z+v.w;
  float s2 = v.x*v.x+v.y*v.y+v.z*v.z+v.w*v.w;
  #pragma unroll
  for (int o=1;o<64;o<<=1){ s1 += __shfl_xor(s1,o); s2 += __shfl_xor(s2,o); }
  __shared__ float sm[8];
  int w = t>>6;
  if ((t&63)==0){ sm[w]=s1; sm[4+w]=s2; }
  __syncthreads();
  s1 = sm[0]+sm[1]+sm[2]+sm[3];
  s2 = sm[4]+sm[5]+sm[6]+sm[7];
  float mu = s1 * (1.0f/D_);
  float var = s2 * (1.0f/D_) - mu*mu;
  float rs = rsqrtf(var + 1e-5f);
  float4 gv = ((const float4*)g)[t];
  float4 bv = ((const float4*)b)[t];
  float4 y;
  y.x = (v.x-mu)*rs*gv.x + bv.x;
  y.y = (v.y-mu)*rs*gv.y + bv.y;
  y.z = (v.z-mu)*rs*gv.z + bv.z;
  y.w = (v.w-mu)*rs*gv.w + bv.w;
  ((float4*)(out + (size_t)blockIdx.x*D_))[t] = y;
}

// ---------------- GEMM: C[m,n] (+)= sum_k A_bf16[m,k] * B_f32[n,k] ----------------
// BM=BN=128, BK=32, 256 threads (4 waves, 2x2), each wave 64x64 via 4x4 MFMA 16x16x32.
// blockIdx.z = mat*kchunks + chunk: mat selects (B,C) pair, chunk selects K-range.
// OP 0: C = acc (kchunks must be 1); OP 1: atomicAdd (residual += or split-K partial).
#define LDA 40   // ushort stride: 80B rows -> 16B aligned, ~2-way banks on b128 reads
template<int OP>
__global__ __launch_bounds__(256) void k_gemm_bt(
    const ushort* __restrict__ A,
    const float* __restrict__ B0, const float* __restrict__ B1, const float* __restrict__ B2,
    float* __restrict__ C0, float* __restrict__ C1, float* __restrict__ C2,
    int N, int K, int kchunks){
  const int z = blockIdx.z;
  const int mat = z / kchunks, chunk = z - mat*kchunks;
  const float* B = (mat==0) ? B0 : ((mat==1) ? B1 : B2);
  float* C = (mat==0) ? C0 : ((mat==1) ? C1 : C2);
  const int Kc = K / kchunks;
  const int kbeg = chunk*Kc, kend = kbeg + Kc;
  const int m0 = blockIdx.x*128, n0 = blockIdx.y*128;
  __shared__ ushort As[128*LDA];
  __shared__ ushort Bs[128*LDA];
  const int t = threadIdx.x;
  const int lane = t & 63, w = t >> 6;
  const int wm = (w & 1)*64, wn = (w >> 1)*64;
  const int fr = lane & 15, fk = (lane >> 4)*8;
  const int trow = t >> 1, tcol = (t & 1)*16;
  const ushort* Ag = A + (size_t)(m0 + trow)*K + tcol;
  const float*  Bg = B + (size_t)(n0 + trow)*K + tcol;
  ushort* Asw = &As[trow*LDA + tcol];
  ushort* Bsw = &Bs[trow*LDA + tcol];

  f32x4 acc[4][4];
  #pragma unroll
  for (int i=0;i<4;i++)
    #pragma unroll
    for (int j=0;j<4;j++)
      #pragma unroll
      for (int r=0;r<4;r++) acc[i][j][r] = 0.0f;

  for (int k0 = kbeg; k0 < kend; k0 += 32){
    uint4 a0 = *(const uint4*)(Ag + k0);
    uint4 a1 = *(const uint4*)(Ag + k0 + 8);
    float4 q0 = *(const float4*)(Bg + k0);
    float4 q1 = *(const float4*)(Bg + k0 + 4);
    float4 q2 = *(const float4*)(Bg + k0 + 8);
    float4 q3 = *(const float4*)(Bg + k0 + 12);
    __syncthreads();   // previous iter's frag reads done
    *(uint4*)(Asw)     = a0;
    *(uint4*)(Asw + 8) = a1;
    *(uint4*)(Bsw)     = pack8(q0, q1);
    *(uint4*)(Bsw + 8) = pack8(q2, q3);
    __syncthreads();
    bf16x8 af[4], bfr[4];
    #pragma unroll
    for (int i=0;i<4;i++) af[i]  = *(const bf16x8*)&As[(wm + i*16 + fr)*LDA + fk];
    #pragma unroll
    for (int j=0;j<4;j++) bfr[j] = *(const bf16x8*)&Bs[(wn + j*16 + fr)*LDA + fk];
    #pragma unroll
    for (int i=0;i<4;i++)
      #pragma unroll
      for (int j=0;j<4;j++)
        acc[i][j] = __builtin_amdgcn_mfma_f32_16x16x32_bf16(af[i], bfr[j], acc[i][j], 0, 0, 0);
  }
  // epilogue: C/D layout col=lane&15, row=(lane>>4)*4+reg
  #pragma unroll
  for (int i=0;i<4;i++){
    int row = m0 + wm + i*16 + (lane >> 4)*4;
    #pragma unroll
    for (int j=0;j<4;j++){
      int col = n0 + wn + j*16 + (lane & 15);
      float* cp = C + (size_t)row*N + col;
      #pragma unroll
      for (int r=0;r<4;r++){
        if (OP == 0) cp[(size_t)r*N] = acc[i][j][r];
        else         atomicAdd(cp + (size_t)r*N, acc[i][j][r]);
      }
    }
  }
}

// ---------------- RoPE (Q and K in one launch) fp32 -> bf16, [b,s,h,d] ----------------
__global__ void k_rope2(const float* __restrict__ qsrc, const float* __restrict__ ksrc,
                        ushort* __restrict__ qdst, ushort* __restrict__ kdst){
  const int half = (B_*S_*D_)/256;
  int bx = blockIdx.x;
  const float* src; ushort* dst;
  if (bx < half){ src = qsrc; dst = qdst; } else { src = ksrc; dst = kdst; bx -= half; }
  int idx = bx*256 + threadIdx.x;
  int d = idx & 63;
  int s = (idx >> 10) & (S_-1);
  float v = src[idx];
  float p = __shfl_xor(v, 32);
  float rot = (d < 32) ? -p : p;
  float inv = expf(-(float)(d & 31) * 0.28782313662f);  // ln(10000)/32
  float sn, cs; sincosf((float)s * inv, &sn, &cs);
  dst[idx] = f2bf(v*cs + rot*sn);
}

// ---------------- V transpose: (b,s,h,d) fp32 -> [bh][d][S] bf16 ----------------
__global__ void k_vt(const float* __restrict__ v, ushort* __restrict__ vt){
  __shared__ float vl[64*68];
  int t = threadIdx.x;
  int s0 = blockIdx.x*64, bh = blockIdx.y;
  int b = bh >> 4, hh = bh & 15;
  int j = t >> 2, off = (t & 3)*16;
  const float* src = v + ((size_t)(b*S_ + s0 + j))*D_ + hh*64 + off;
  float4 r0 = ((const float4*)src)[0];
  float4 r1 = ((const float4*)src)[1];
  float4 r2 = ((const float4*)src)[2];
  float4 r3 = ((const float4*)src)[3];
  *(float4*)&vl[j*68 + off +  0] = r0;
  *(float4*)&vl[j*68 + off +  4] = r1;
  *(float4*)&vl[j*68 + off +  8] = r2;
  *(float4*)&vl[j*68 + off + 12] = r3;
  __syncthreads();
  int d = t >> 2, so = (t & 3)*16;
  ushort* dst = vt + ((size_t)bh*64 + d)*S_ + s0 + so;
  union { ushort u[8]; uint4 q; } o0, o1;
  #pragma unroll
  for (int jj=0; jj<8; jj++) o0.u[jj] = f2bf(vl[(so + jj)*68 + d]);
  #pragma unroll
  for (int jj=0; jj<8; jj++) o1.u[jj] = f2bf(vl[(so + 8 + jj)*68 + d]);
  *(uint4*)dst       = o0.q;
  *(uint4*)(dst + 8) = o1.q;
}

// ---------------- MFMA flash attention (causal, online softmax) -> bf16 ctx -------
// Block: 64 queries of one (b,h), 4 waves x 16 queries. K/V chunks of 64 in LDS.
// Per wave per chunk: 8 MFMA (QK^T) + online softmax (16-lane reduces) + 8 MFMA (PV).
// Fragment layout (verified in k_gemm_bt): A/B row=lane&15, k=(lane>>4)*8;
//                                          C/D col=lane&15, row=(lane>>4)*4+reg.
#define LDK 72   // ushort stride: 144B rows, 16B aligned, GEMM-class bank pattern
__global__ __launch_bounds__(256) void k_flash(
    const ushort* __restrict__ qh, const ushort* __restrict__ kh,
    const ushort* __restrict__ vt, ushort* __restrict__ ctx){
  __shared__ ushort Kl[64*LDK];      // [key][d]
  __shared__ ushort Vl[64*LDK];      // [d][key]
  __shared__ ushort Pl[4][16*LDK];   // per-wave [q][key]
  const int t = threadIdx.x, lane = t & 63, w = t >> 6;
  const int bh = blockIdx.x, b = bh >> 4, hh = bh & 15;
  // balanced causal schedule: blocks i and i+256 sum to a constant 17 chunks
  const int yy = blockIdx.y;
  const int q0 = 64 * ((yy < 8) ? (15 - 2*yy) : (2*yy - 16));
  const int qw = q0 + w*16;
  const int fr = lane & 15, fk = (lane >> 4)*8;
  bf16x8 qf0, qf1;
  {
    const ushort* qp = qh + ((size_t)(b*S_ + qw + fr))*D_ + hh*64;
    qf0 = *(const bf16x8*)(qp + fk);
    qf1 = *(const bf16x8*)(qp + 32 + fk);
  }
  f32x4 o[4];
  float m[4], l[4];
  #pragma unroll
  for (int r=0;r<4;r++){
    m[r] = -1e30f; l[r] = 0.f;
    #pragma unroll
    for (int j=0;j<4;j++) o[j][r] = 0.f;
  }
  const int nch = q0/64 + 1;
  const int sr = t >> 2, soff = (t & 3)*16;
  ushort* Plw = Pl[w];
  const int rbase = qw + (lane >> 4)*4;
  for (int c=0; c<nch; c++){
    const int k0 = c*64;
    __syncthreads();
    {
      const uint4* ks = (const uint4*)(kh + ((size_t)(b*S_ + k0 + sr))*D_ + hh*64 + soff);
      uint4 ka = ks[0], kb2 = ks[1];
      const uint4* vs = (const uint4*)(vt + ((size_t)(bh*64 + sr))*S_ + k0 + soff);
      uint4 va = vs[0], vb2 = vs[1];
      *(uint4*)&Kl[sr*LDK + soff]     = ka;
      *(uint4*)&Kl[sr*LDK + soff + 8] = kb2;
      *(uint4*)&Vl[sr*LDK + soff]     = va;
      *(uint4*)&Vl[sr*LDK + soff + 8] = vb2;
    }
    __syncthreads();
    // S = Q K^T  (16q x 64k per wave)
    f32x4 sc[4];
    #pragma unroll
    for (int j=0;j<4;j++){
      bf16x8 kf0 = *(const bf16x8*)&Kl[(j*16 + fr)*LDK + fk];
      bf16x8 kf1 = *(const bf16x8*)&Kl[(j*16 + fr)*LDK + 32 + fk];
      f32x4 z; z[0]=0.f; z[1]=0.f; z[2]=0.f; z[3]=0.f;
      z = __builtin_amdgcn_mfma_f32_16x16x32_bf16(qf0, kf0, z, 0, 0, 0);
      sc[j] = __builtin_amdgcn_mfma_f32_16x16x32_bf16(qf1, kf1, z, 0, 0, 0);
    }
    // online softmax per query row (rows live in 16-lane groups)
    #pragma unroll
    for (int r=0;r<4;r++){
      const int qrow = rbase + r;
      float mc = -1e30f;
      #pragma unroll
      for (int j=0;j<4;j++){
        float sv = (k0 + j*16 + fr <= qrow) ? sc[j][r]*0.125f : -1e30f;
        sc[j][r] = sv;
        mc = fmaxf(mc, sv);
      }
      #pragma unroll
      for (int ofs=1; ofs<16; ofs<<=1) mc = fmaxf(mc, __shfl_xor(mc, ofs));
      float mn = fmaxf(m[r], mc);
      float al = expf(m[r] - mn);
      float sum = 0.f;
      #pragma unroll
      for (int j=0;j<4;j++){
        float p = expf(sc[j][r] - mn);
        sum += p;
        Plw[(((lane >> 4)*4) + r)*LDK + j*16 + fr] = f2bf(p);
      }
      #pragma unroll
      for (int ofs=1; ofs<16; ofs<<=1) sum += __shfl_xor(sum, ofs);
      l[r] = l[r]*al + sum;
      m[r] = mn;
      #pragma unroll
      for (int j=0;j<4;j++) o[j][r] *= al;
    }
    // O += P V   (P via wave-private LDS bounce to A-fragment layout; no barrier
    // needed: same-wave LDS RAW is ordered by lgkmcnt)
    bf16x8 pa0 = *(const bf16x8*)&Plw[fr*LDK + fk];
    bf16x8 pa1 = *(const bf16x8*)&Plw[fr*LDK + 32 + fk];
    #pragma unroll
    for (int j=0;j<4;j++){
      bf16x8 vf0 = *(const bf16x8*)&Vl[(j*16 + fr)*LDK + fk];
      bf16x8 vf1 = *(const bf16x8*)&Vl[(j*16 + fr)*LDK + 32 + fk];
      o[j] = __builtin_amdgcn_mfma_f32_16x16x32_bf16(pa0, vf0, o[j], 0, 0, 0);
      o[j] = __builtin_amdgcn_mfma_f32_16x16x32_bf16(pa1, vf1, o[j], 0, 0, 0);
    }
  }
  #pragma unroll
  for (int r=0;r<4;r++){
    float rl = 1.0f / l[r];
    ushort* cp = ctx + ((size_t)(b*S_ + rbase + r))*D_ + hh*64 + fr;
    #pragma unroll
    for (int j=0;j<4;j++) cp[j*16] = f2bf(o[j][r] * rl);
  }
}

// ---------------- silu(g1) * g3 -> bf16 ----------------
__global__ void k_silu(const float* __restrict__ g1, const float* __restrict__ g3,
                       ushort* __restrict__ p){
  int idx = blockIdx.x*256 + threadIdx.x;
  float4 a = ((const float4*)g1)[idx];
  float4 b = ((const float4*)g3)[idx];
  union { ushort u[4]; uint2 v; } o;
  o.u[0] = f2bf(a.x / (1.f + expf(-a.x)) * b.x);
  o.u[1] = f2bf(a.y / (1.f + expf(-a.y)) * b.y);
  o.u[2] = f2bf(a.z / (1.f + expf(-a.z)) * b.z);
  o.u[3] = f2bf(a.w / (1.f + expf(-a.w)) * b.w);
  ((uint2*)p)[idx] = o.v;
}

extern "C" void kernel_launch(void* const* d_in, const int* in_sizes, int n_in,
                              void* d_out, int out_size, void* d_ws, size_t ws_size,
                              hipStream_t stream) {
  const int*   ids  = (const int*)  d_in[0];
  const float* tok  = (const float*)d_in[1];
  const float* pos  = (const float*)d_in[2];
  const float* wq   = (const float*)d_in[3];
  const float* wk   = (const float*)d_in[4];
  const float* wv   = (const float*)d_in[5];
  const float* wo   = (const float*)d_in[6];
  const float* w1   = (const float*)d_in[7];
  const float* w2   = (const float*)d_in[8];
  const float* w3   = (const float*)d_in[9];
  const float* ln1g = (const float*)d_in[10];
  const float* ln1b = (const float*)d_in[11];
  const float* ln2g = (const float*)d_in[12];
  const float* ln2b = (const float*)d_in[13];
  const float* lnfg = (const float*)d_in[14];
  const float* lnfb = (const float*)d_in[15];

  char* wsb = (char*)d_ws;
  float*  x  = (float*) (wsb);                               // 8 MB
  ushort* h  = (ushort*)(wsb + (size_t)8*1024*1024);         // 4 MB
  float*  qb = (float*) (wsb + (size_t)12*1024*1024);        // 8 MB
  float*  kb = (float*) (wsb + (size_t)20*1024*1024);        // 8 MB
  float*  vb = (float*) (wsb + (size_t)28*1024*1024);        // 8 MB
  ushort* qh = (ushort*)(wsb + (size_t)36*1024*1024);        // 4 MB bf16 Q (post-RoPE)
  ushort* kh = (ushort*)(wsb + (size_t)40*1024*1024);        // 4 MB bf16 K (post-RoPE)
  ushort* vt = (ushort*)(wsb + (size_t)12*1024*1024);        // 4 MB bf16 V^T, aliases qb (dead after k_rope2)
  ushort* cx = (ushort*)(wsb + (size_t)44*1024*1024);        // 4 MB
  float*  g1 = (float*) (wsb + (size_t)48*1024*1024);        // 32 MB
  float*  g3 = (float*) (wsb + (size_t)80*1024*1024);        // 32 MB
  ushort* pb = (ushort*)(wsb + (size_t)112*1024*1024);       // 16 MB -> total 128 MB

  k_embed<<<B_*S_, 256, 0, stream>>>(ids, tok, pos, x);

  for (int l = 0; l < L_; l++){
    size_t od = (size_t)l*D_*D_;
    size_t fd = (size_t)l*F_*D_;
    // zero qb/kb/vb (24 MB contiguous) for split-K atomic QKV
    hipMemsetAsync(qb, 0, (size_t)24*1024*1024, stream);
    k_ln<<<B_*S_, 256, 0, stream>>>(x, ln1g + l*D_, ln1b + l*D_, h);
    // fused Q/K/V, split-K x2 -> 768 blocks
    k_gemm_bt<1><<<dim3(16, 8, 6), 256, 0, stream>>>(h, wq + od, wk + od, wv + od,
                                                     qb, kb, vb, D_, D_, 2);
    k_rope2<<<2*(B_*S_*D_)/256, 256, 0, stream>>>(qb, kb, qh, kh);
    k_vt<<<dim3(S_/64, B_*H_), 256, 0, stream>>>(vb, vt);
    k_flash<<<dim3(B_*H_, S_/64), 256, 0, stream>>>(qh, kh, vt, cx);
    // attn out projection + residual, split-K x4 -> 512 blocks
    k_gemm_bt<1><<<dim3(16, 8, 4), 256, 0, stream>>>(cx, wo + od, nullptr, nullptr,
                                                     x, nullptr, nullptr, D_, D_, 4);
    k_ln<<<B_*S_, 256, 0, stream>>>(x, ln2g + l*D_, ln2b + l*D_, h);
    // fused W1/W3 (1024 blocks already)
    k_gemm_bt<0><<<dim3(16, 32, 2), 256, 0, stream>>>(h, w1 + fd, w3 + fd, nullptr,
                                                      g1, g3, nullptr, F_, D_, 1);
    k_silu<<<(B_*S_*F_)/1024, 256, 0, stream>>>(g1, g3, pb);
    // W2 + residual, split-K x8 -> 1024 blocks
    k_gemm_bt<1><<<dim3(16, 8, 8), 256, 0, stream>>>(pb, w2 + fd, nullptr, nullptr,
                                                     x, nullptr, nullptr, D_, F_, 8);
  }

  k_lnf<<<B_, 256, 0, stream>>>(x, lnfg, lnfb, (float*)d_out);
}

// Round 3
// 2285.971 us; speedup vs baseline: 2.1463x; 1.0769x over previous
//
#include <hip/hip_runtime.h>
#include <hip/hip_bf16.h>

#define D_ 1024
#define S_ 1024
#define B_ 2
#define H_ 16
#define F_ 4096
#define L_ 6

typedef __bf16 bf16x8 __attribute__((ext_vector_type(8)));
typedef float f32x4 __attribute__((ext_vector_type(4)));

__device__ __forceinline__ unsigned short f2bf(float f){
  union { float f; unsigned u; } v; v.f = f;
  unsigned r = v.u + 0x7fffu + ((v.u >> 16) & 1u);
  return (unsigned short)(r >> 16);
}
__device__ __forceinline__ uint pk2(float lo, float hi){
  return (uint)f2bf(lo) | ((uint)f2bf(hi) << 16);
}
__device__ __forceinline__ uint4 pack8(float4 a, float4 b){
  uint4 r; r.x = pk2(a.x,a.y); r.y = pk2(a.z,a.w); r.z = pk2(b.x,b.y); r.w = pk2(b.z,b.w); return r;
}

// ---------------- embedding ----------------
__global__ void k_embed(const int* __restrict__ ids, const float* __restrict__ tok,
                        const float* __restrict__ pos, float* __restrict__ x){
  int row = blockIdx.x;            // b*S + s
  int s = row & (S_-1);
  int id = ids[row];
  int t = threadIdx.x;
  float4 te = ((const float4*)(tok + (size_t)id*D_))[t];
  float4 pe = ((const float4*)(pos + (size_t)s*D_))[t];
  float4 o; o.x=te.x+pe.x; o.y=te.y+pe.y; o.z=te.z+pe.z; o.w=te.w+pe.w;
  ((float4*)(x + (size_t)row*D_))[t] = o;
}

// ---------------- layernorm -> bf16 ----------------
__global__ void k_ln(const float* __restrict__ x, const float* __restrict__ g,
                     const float* __restrict__ b, ushort* __restrict__ h){
  int row = blockIdx.x;
  int t = threadIdx.x;
  float4 v = ((const float4*)(x + (size_t)row*D_))[t];
  float s1 = v.x+v.y+v.z+v.w;
  float s2 = v.x*v.x+v.y*v.y+v.z*v.z+v.w*v.w;
  #pragma unroll
  for (int o=1;o<64;o<<=1){ s1 += __shfl_xor(s1,o); s2 += __shfl_xor(s2,o); }
  __shared__ float sm[8];
  int w = t>>6;
  if ((t&63)==0){ sm[w]=s1; sm[4+w]=s2; }
  __syncthreads();
  s1 = sm[0]+sm[1]+sm[2]+sm[3];
  s2 = sm[4]+sm[5]+sm[6]+sm[7];
  float mu = s1 * (1.0f/D_);
  float var = s2 * (1.0f/D_) - mu*mu;
  float rs = rsqrtf(var + 1e-5f);
  float4 gv = ((const float4*)g)[t];
  float4 bv = ((const float4*)b)[t];
  union { ushort u[4]; uint2 p; } o;
  o.u[0] = f2bf((v.x-mu)*rs*gv.x + bv.x);
  o.u[1] = f2bf((v.y-mu)*rs*gv.y + bv.y);
  o.u[2] = f2bf((v.z-mu)*rs*gv.z + bv.z);
  o.u[3] = f2bf((v.w-mu)*rs*gv.w + bv.w);
  ((uint2*)(h + (size_t)row*D_))[t] = o.p;
}

// ---------------- final layernorm (last token per batch) -> fp32 out ----------------
__global__ void k_lnf(const float* __restrict__ x, const float* __restrict__ g,
                      const float* __restrict__ b, float* __restrict__ out){
  int row = blockIdx.x*S_ + (S_-1);
  int t = threadIdx.x;
  float4 v = ((const float4*)(x + (size_t)row*D_))[t];
  float s1 = v.x+v.y+v.z+v.w;
  float s2 = v.x*v.x+v.y*v.y+v.z*v.z+v.w*v.w;
  #pragma unroll
  for (int o=1;o<64;o<<=1){ s1 += __shfl_xor(s1,o); s2 += __shfl_xor(s2,o); }
  __shared__ float sm[8];
  int w = t>>6;
  if ((t&63)==0){ sm[w]=s1; sm[4+w]=s2; }
  __syncthreads();
  s1 = sm[0]+sm[1]+sm[2]+sm[3];
  s2 = sm[4]+sm[5]+sm[6]+sm[7];
  float mu = s1 * (1.0f/D_);
  float var = s2 * (1.0f/D_) - mu*mu;
  float rs = rsqrtf(var + 1e-5f);
  float4 gv = ((const float4*)g)[t];
  float4 bv = ((const float4*)b)[t];
  float4 y;
  y.x = (v.x-mu)*rs*gv.x + bv.x;
  y.y = (v.y-mu)*rs*gv.y + bv.y;
  y.z = (v.z-mu)*rs*gv.z + bv.z;
  y.w = (v.w-mu)*rs*gv.w + bv.w;
  ((float4*)(out + (size_t)blockIdx.x*D_))[t] = y;
}

// ---------------- GEMM: C[m,n] (+)= sum_k A_bf16[m,k] * B_f32[n,k] ----------------
// BM=BN=128, BK=32, 256 threads (4 waves, 2x2), each wave 64x64 via 4x4 MFMA 16x16x32.
// blockIdx.z = mat*kchunks + chunk: mat selects (B,C) pair, chunk selects K-range.
// OP 0: C[+chunk*coff] = acc (split-K partials to disjoint regions, no atomics).
// OP 1: atomicAdd into C (residual += / split-K into live accumulator).
#define LDA 40   // ushort stride: 80B rows -> 16B aligned, ~2-way banks on b128 reads
template<int OP>
__global__ __launch_bounds__(256) void k_gemm_bt(
    const ushort* __restrict__ A,
    const float* __restrict__ B0, const float* __restrict__ B1, const float* __restrict__ B2,
    float* __restrict__ C0, float* __restrict__ C1, float* __restrict__ C2,
    int N, int K, int kchunks, int coff){
  const int z = blockIdx.z;
  const int mat = z / kchunks, chunk = z - mat*kchunks;
  const float* B = (mat==0) ? B0 : ((mat==1) ? B1 : B2);
  float* C = (mat==0) ? C0 : ((mat==1) ? C1 : C2);
  if (OP == 0) C += (size_t)chunk * coff;
  const int Kc = K / kchunks;
  const int kbeg = chunk*Kc, kend = kbeg + Kc;
  const int m0 = blockIdx.x*128, n0 = blockIdx.y*128;
  __shared__ ushort As[128*LDA];
  __shared__ ushort Bs[128*LDA];
  const int t = threadIdx.x;
  const int lane = t & 63, w = t >> 6;
  const int wm = (w & 1)*64, wn = (w >> 1)*64;
  const int fr = lane & 15, fk = (lane >> 4)*8;
  const int trow = t >> 1, tcol = (t & 1)*16;
  const ushort* Ag = A + (size_t)(m0 + trow)*K + tcol;
  const float*  Bg = B + (size_t)(n0 + trow)*K + tcol;
  ushort* Asw = &As[trow*LDA + tcol];
  ushort* Bsw = &Bs[trow*LDA + tcol];

  f32x4 acc[4][4];
  #pragma unroll
  for (int i=0;i<4;i++)
    #pragma unroll
    for (int j=0;j<4;j++)
      #pragma unroll
      for (int r=0;r<4;r++) acc[i][j][r] = 0.0f;

  for (int k0 = kbeg; k0 < kend; k0 += 32){
    uint4 a0 = *(const uint4*)(Ag + k0);
    uint4 a1 = *(const uint4*)(Ag + k0 + 8);
    float4 q0 = *(const float4*)(Bg + k0);
    float4 q1 = *(const float4*)(Bg + k0 + 4);
    float4 q2 = *(const float4*)(Bg + k0 + 8);
    float4 q3 = *(const float4*)(Bg + k0 + 12);
    __syncthreads();   // previous iter's frag reads done
    *(uint4*)(Asw)     = a0;
    *(uint4*)(Asw + 8) = a1;
    *(uint4*)(Bsw)     = pack8(q0, q1);
    *(uint4*)(Bsw + 8) = pack8(q2, q3);
    __syncthreads();
    bf16x8 af[4], bfr[4];
    #pragma unroll
    for (int i=0;i<4;i++) af[i]  = *(const bf16x8*)&As[(wm + i*16 + fr)*LDA + fk];
    #pragma unroll
    for (int j=0;j<4;j++) bfr[j] = *(const bf16x8*)&Bs[(wn + j*16 + fr)*LDA + fk];
    #pragma unroll
    for (int i=0;i<4;i++)
      #pragma unroll
      for (int j=0;j<4;j++)
        acc[i][j] = __builtin_amdgcn_mfma_f32_16x16x32_bf16(af[i], bfr[j], acc[i][j], 0, 0, 0);
  }
  // epilogue: C/D layout col=lane&15, row=(lane>>4)*4+reg
  #pragma unroll
  for (int i=0;i<4;i++){
    int row = m0 + wm + i*16 + (lane >> 4)*4;
    #pragma unroll
    for (int j=0;j<4;j++){
      int col = n0 + wn + j*16 + (lane & 15);
      float* cp = C + (size_t)row*N + col;
      #pragma unroll
      for (int r=0;r<4;r++){
        if (OP == 0) cp[(size_t)r*N] = acc[i][j][r];
        else         atomicAdd(cp + (size_t)r*N, acc[i][j][r]);
      }
    }
  }
}

// ---------------- sum 2 QKV partials + RoPE (Q and K) -> bf16 [b,s,h,d] ----------------
__global__ void k_rope2p(const float* __restrict__ q0, const float* __restrict__ q1,
                         const float* __restrict__ kp0, const float* __restrict__ kp1,
                         ushort* __restrict__ qdst, ushort* __restrict__ kdst){
  const int half = (B_*S_*D_)/256;
  int bx = blockIdx.x;
  const float *src0, *src1; ushort* dst;
  if (bx < half){ src0 = q0; src1 = q1; dst = qdst; }
  else          { src0 = kp0; src1 = kp1; dst = kdst; bx -= half; }
  int idx = bx*256 + threadIdx.x;
  int d = idx & 63;
  int s = (idx >> 10) & (S_-1);
  float v = src0[idx] + src1[idx];
  float p = __shfl_xor(v, 32);
  float rot = (d < 32) ? -p : p;
  float inv = expf(-(float)(d & 31) * 0.28782313662f);  // ln(10000)/32
  float sn, cs; sincosf((float)s * inv, &sn, &cs);
  dst[idx] = f2bf(v*cs + rot*sn);
}

// ---------------- sum 2 V partials + transpose: (b,s,h,d) -> [bh][d][S] bf16 ---------
__global__ void k_vt(const float* __restrict__ v0, const float* __restrict__ v1,
                     ushort* __restrict__ vt){
  __shared__ float vl[64*68];
  int t = threadIdx.x;
  int s0 = blockIdx.x*64, bh = blockIdx.y;
  int b = bh >> 4, hh = bh & 15;
  int j = t >> 2, off = (t & 3)*16;
  size_t sidx = ((size_t)(b*S_ + s0 + j))*D_ + hh*64 + off;
  const float* sa = v0 + sidx;
  const float* sb = v1 + sidx;
  #pragma unroll
  for (int q=0; q<4; q++){
    float4 ra = ((const float4*)sa)[q];
    float4 rb = ((const float4*)sb)[q];
    float4 rs; rs.x=ra.x+rb.x; rs.y=ra.y+rb.y; rs.z=ra.z+rb.z; rs.w=ra.w+rb.w;
    *(float4*)&vl[j*68 + off + q*4] = rs;
  }
  __syncthreads();
  int d = t >> 2, so = (t & 3)*16;
  ushort* dst = vt + ((size_t)bh*64 + d)*S_ + s0 + so;
  union { ushort u[8]; uint4 q; } o0, o1;
  #pragma unroll
  for (int jj=0; jj<8; jj++) o0.u[jj] = f2bf(vl[(so + jj)*68 + d]);
  #pragma unroll
  for (int jj=0; jj<8; jj++) o1.u[jj] = f2bf(vl[(so + 8 + jj)*68 + d]);
  *(uint4*)dst       = o0.q;
  *(uint4*)(dst + 8) = o1.q;
}

// ---------------- MFMA flash attention (causal, online softmax) -> bf16 ctx -------
// Block: 64 queries of one (b,h), 4 waves x 16 queries. K/V chunks of 64 in LDS.
// Per wave per chunk: 8 MFMA (QK^T) + online softmax (16-lane reduces) + 8 MFMA (PV).
// Fragment layout (verified in k_gemm_bt): A/B row=lane&15, k=(lane>>4)*8;
//                                          C/D col=lane&15, row=(lane>>4)*4+reg.
#define LDK 72   // ushort stride: 144B rows, 16B aligned, GEMM-class bank pattern
__global__ __launch_bounds__(256) void k_flash(
    const ushort* __restrict__ qh, const ushort* __restrict__ kh,
    const ushort* __restrict__ vt, ushort* __restrict__ ctx){
  __shared__ ushort Kl[64*LDK];      // [key][d]
  __shared__ ushort Vl[64*LDK];      // [d][key]
  __shared__ ushort Pl[4][16*LDK];   // per-wave [q][key]
  const int t = threadIdx.x, lane = t & 63, w = t >> 6;
  const int bh = blockIdx.x, b = bh >> 4, hh = bh & 15;
  // balanced causal schedule: blocks i and i+256 sum to a constant 17 chunks
  const int yy = blockIdx.y;
  const int q0 = 64 * ((yy < 8) ? (15 - 2*yy) : (2*yy - 16));
  const int qw = q0 + w*16;
  const int fr = lane & 15, fk = (lane >> 4)*8;
  bf16x8 qf0, qf1;
  {
    const ushort* qp = qh + ((size_t)(b*S_ + qw + fr))*D_ + hh*64;
    qf0 = *(const bf16x8*)(qp + fk);
    qf1 = *(const bf16x8*)(qp + 32 + fk);
  }
  f32x4 o[4];
  float m[4], l[4];
  #pragma unroll
  for (int r=0;r<4;r++){
    m[r] = -1e30f; l[r] = 0.f;
    #pragma unroll
    for (int j=0;j<4;j++) o[j][r] = 0.f;
  }
  const int nch = q0/64 + 1;
  const int sr = t >> 2, soff = (t & 3)*16;
  ushort* Plw = Pl[w];
  const int rbase = qw + (lane >> 4)*4;
  for (int c=0; c<nch; c++){
    const int k0 = c*64;
    __syncthreads();
    {
      const uint4* ks = (const uint4*)(kh + ((size_t)(b*S_ + k0 + sr))*D_ + hh*64 + soff);
      uint4 ka = ks[0], kb2 = ks[1];
      const uint4* vs = (const uint4*)(vt + ((size_t)(bh*64 + sr))*S_ + k0 + soff);
      uint4 va = vs[0], vb2 = vs[1];
      *(uint4*)&Kl[sr*LDK + soff]     = ka;
      *(uint4*)&Kl[sr*LDK + soff + 8] = kb2;
      *(uint4*)&Vl[sr*LDK + soff]     = va;
      *(uint4*)&Vl[sr*LDK + soff + 8] = vb2;
    }
    __syncthreads();
    // S = Q K^T  (16q x 64k per wave)
    f32x4 sc[4];
    #pragma unroll
    for (int j=0;j<4;j++){
      bf16x8 kf0 = *(const bf16x8*)&Kl[(j*16 + fr)*LDK + fk];
      bf16x8 kf1 = *(const bf16x8*)&Kl[(j*16 + fr)*LDK + 32 + fk];
      f32x4 z; z[0]=0.f; z[1]=0.f; z[2]=0.f; z[3]=0.f;
      z = __builtin_amdgcn_mfma_f32_16x16x32_bf16(qf0, kf0, z, 0, 0, 0);
      sc[j] = __builtin_amdgcn_mfma_f32_16x16x32_bf16(qf1, kf1, z, 0, 0, 0);
    }
    // online softmax per query row (rows live in 16-lane groups)
    #pragma unroll
    for (int r=0;r<4;r++){
      const int qrow = rbase + r;
      float mc = -1e30f;
      #pragma unroll
      for (int j=0;j<4;j++){
        float sv = (k0 + j*16 + fr <= qrow) ? sc[j][r]*0.125f : -1e30f;
        sc[j][r] = sv;
        mc = fmaxf(mc, sv);
      }
      #pragma unroll
      for (int ofs=1; ofs<16; ofs<<=1) mc = fmaxf(mc, __shfl_xor(mc, ofs));
      float mn = fmaxf(m[r], mc);
      float al = expf(m[r] - mn);
      float sum = 0.f;
      #pragma unroll
      for (int j=0;j<4;j++){
        float p = expf(sc[j][r] - mn);
        sum += p;
        Plw[(((lane >> 4)*4) + r)*LDK + j*16 + fr] = f2bf(p);
      }
      #pragma unroll
      for (int ofs=1; ofs<16; ofs<<=1) sum += __shfl_xor(sum, ofs);
      l[r] = l[r]*al + sum;
      m[r] = mn;
      #pragma unroll
      for (int j=0;j<4;j++) o[j][r] *= al;
    }
    // O += P V   (P via wave-private LDS bounce to A-fragment layout; no barrier
    // needed: same-wave LDS RAW is ordered by lgkmcnt)
    bf16x8 pa0 = *(const bf16x8*)&Plw[fr*LDK + fk];
    bf16x8 pa1 = *(const bf16x8*)&Plw[fr*LDK + 32 + fk];
    #pragma unroll
    for (int j=0;j<4;j++){
      bf16x8 vf0 = *(const bf16x8*)&Vl[(j*16 + fr)*LDK + fk];
      bf16x8 vf1 = *(const bf16x8*)&Vl[(j*16 + fr)*LDK + 32 + fk];
      o[j] = __builtin_amdgcn_mfma_f32_16x16x32_bf16(pa0, vf0, o[j], 0, 0, 0);
      o[j] = __builtin_amdgcn_mfma_f32_16x16x32_bf16(pa1, vf1, o[j], 0, 0, 0);
    }
  }
  #pragma unroll
  for (int r=0;r<4;r++){
    float rl = 1.0f / l[r];
    ushort* cp = ctx + ((size_t)(b*S_ + rbase + r))*D_ + hh*64 + fr;
    #pragma unroll
    for (int j=0;j<4;j++) cp[j*16] = f2bf(o[j][r] * rl);
  }
}

// ---------------- silu(g1) * g3 -> bf16 ----------------
__global__ void k_silu(const float* __restrict__ g1, const float* __restrict__ g3,
                       ushort* __restrict__ p){
  int idx = blockIdx.x*256 + threadIdx.x;
  float4 a = ((const float4*)g1)[idx];
  float4 b = ((const float4*)g3)[idx];
  union { ushort u[4]; uint2 v; } o;
  o.u[0] = f2bf(a.x / (1.f + expf(-a.x)) * b.x);
  o.u[1] = f2bf(a.y / (1.f + expf(-a.y)) * b.y);
  o.u[2] = f2bf(a.z / (1.f + expf(-a.z)) * b.z);
  o.u[3] = f2bf(a.w / (1.f + expf(-a.w)) * b.w);
  ((uint2*)p)[idx] = o.v;
}

extern "C" void kernel_launch(void* const* d_in, const int* in_sizes, int n_in,
                              void* d_out, int out_size, void* d_ws, size_t ws_size,
                              hipStream_t stream) {
  const int*   ids  = (const int*)  d_in[0];
  const float* tok  = (const float*)d_in[1];
  const float* pos  = (const float*)d_in[2];
  const float* wq   = (const float*)d_in[3];
  const float* wk   = (const float*)d_in[4];
  const float* wv   = (const float*)d_in[5];
  const float* wo   = (const float*)d_in[6];
  const float* w1   = (const float*)d_in[7];
  const float* w2   = (const float*)d_in[8];
  const float* w3   = (const float*)d_in[9];
  const float* ln1g = (const float*)d_in[10];
  const float* ln1b = (const float*)d_in[11];
  const float* ln2g = (const float*)d_in[12];
  const float* ln2b = (const float*)d_in[13];
  const float* lnfg = (const float*)d_in[14];
  const float* lnfb = (const float*)d_in[15];

  char* wsb = (char*)d_ws;
  float*  x  = (float*) (wsb);                               // 8 MB
  ushort* h  = (ushort*)(wsb + (size_t)8*1024*1024);         // 4 MB bf16 LN output
  ushort* vt = (ushort*)(wsb + (size_t)12*1024*1024);        // 4 MB bf16 V^T
  ushort* qh = (ushort*)(wsb + (size_t)16*1024*1024);        // 4 MB bf16 Q (post-RoPE)
  ushort* kh = (ushort*)(wsb + (size_t)20*1024*1024);        // 4 MB bf16 K (post-RoPE)
  ushort* cx = (ushort*)(wsb + (size_t)24*1024*1024);        // 4 MB bf16 ctx
  float*  g1 = (float*) (wsb + (size_t)48*1024*1024);        // 32 MB
  float*  g3 = (float*) (wsb + (size_t)80*1024*1024);        // 32 MB
  ushort* pb = (ushort*)(wsb + (size_t)112*1024*1024);       // 16 MB -> total 128 MB

  // QKV split-K partials live in the (currently dead) g1/g3 regions:
  // chunk c of matrix m at g1 + c*8M floats + m*2M floats  (3 x 8 MB per chunk)
  const int QKV_COFF = 8*1024*1024;                 // floats: 32 MB chunk stride
  float* qp = g1;                                   // q partials
  float* kp = g1 + 2*1024*1024;                     // k partials
  float* vp = g1 + 4*1024*1024;                     // v partials

  k_embed<<<B_*S_, 256, 0, stream>>>(ids, tok, pos, x);

  for (int l = 0; l < L_; l++){
    size_t od = (size_t)l*D_*D_;
    size_t fd = (size_t)l*F_*D_;
    k_ln<<<B_*S_, 256, 0, stream>>>(x, ln1g + l*D_, ln1b + l*D_, h);
    // fused Q/K/V, split-K x2 -> 768 blocks, partials to disjoint regions (no atomics)
    k_gemm_bt<0><<<dim3(16, 8, 6), 256, 0, stream>>>(h, wq + od, wk + od, wv + od,
                                                     qp, kp, vp, D_, D_, 2, QKV_COFF);
    k_rope2p<<<2*(B_*S_*D_)/256, 256, 0, stream>>>(qp, qp + QKV_COFF, kp, kp + QKV_COFF,
                                                   qh, kh);
    k_vt<<<dim3(S_/64, B_*H_), 256, 0, stream>>>(vp, vp + QKV_COFF, vt);
    k_flash<<<dim3(B_*H_, S_/64), 256, 0, stream>>>(qh, kh, vt, cx);
    // attn out projection + residual, split-K x4 -> 512 blocks (atomic into live x)
    k_gemm_bt<1><<<dim3(16, 8, 4), 256, 0, stream>>>(cx, wo + od, nullptr, nullptr,
                                                     x, nullptr, nullptr, D_, D_, 4, 0);
    k_ln<<<B_*S_, 256, 0, stream>>>(x, ln2g + l*D_, ln2b + l*D_, h);
    // fused W1/W3 (1024 blocks already) -- overwrites the QKV partial regions (dead)
    k_gemm_bt<0><<<dim3(16, 32, 2), 256, 0, stream>>>(h, w1 + fd, w3 + fd, nullptr,
                                                      g1, g3, nullptr, F_, D_, 1, 0);
    k_silu<<<(B_*S_*F_)/1024, 256, 0, stream>>>(g1, g3, pb);
    // W2 + residual, split-K x8 -> 1024 blocks (atomic into live x)
    k_gemm_bt<1><<<dim3(16, 8, 8), 256, 0, stream>>>(pb, w2 + fd, nullptr, nullptr,
                                                     x, nullptr, nullptr, D_, F_, 8, 0);
  }

  k_lnf<<<B_, 256, 0, stream>>>(x, lnfg, lnfb, (float*)d_out);
}

// Round 4
// 2253.044 us; speedup vs baseline: 2.1777x; 1.0146x over previous
//
#include <hip/hip_runtime.h>
#include <hip/hip_bf16.h>

#define D_ 1024
#define S_ 1024
#define B_ 2
#define H_ 16
#define F_ 4096
#define L_ 6

typedef __bf16 bf16x8 __attribute__((ext_vector_type(8)));
typedef float f32x4 __attribute__((ext_vector_type(4)));

__device__ __forceinline__ unsigned short f2bf(float f){
  union { float f; unsigned u; } v; v.f = f;
  unsigned r = v.u + 0x7fffu + ((v.u >> 16) & 1u);
  return (unsigned short)(r >> 16);
}
__device__ __forceinline__ uint pk2(float lo, float hi){
  return (uint)f2bf(lo) | ((uint)f2bf(hi) << 16);
}
__device__ __forceinline__ uint4 pack8(float4 a, float4 b){
  uint4 r; r.x = pk2(a.x,a.y); r.y = pk2(a.z,a.w); r.z = pk2(b.x,b.y); r.w = pk2(b.z,b.w); return r;
}

// ---------------- embedding ----------------
__global__ void k_embed(const int* __restrict__ ids, const float* __restrict__ tok,
                        const float* __restrict__ pos, float* __restrict__ x){
  int row = blockIdx.x;            // b*S + s
  int s = row & (S_-1);
  int id = ids[row];
  int t = threadIdx.x;
  float4 te = ((const float4*)(tok + (size_t)id*D_))[t];
  float4 pe = ((const float4*)(pos + (size_t)s*D_))[t];
  float4 o; o.x=te.x+pe.x; o.y=te.y+pe.y; o.z=te.z+pe.z; o.w=te.w+pe.w;
  ((float4*)(x + (size_t)row*D_))[t] = o;
}

// ---------------- layernorm -> bf16 ----------------
__global__ void k_ln(const float* __restrict__ x, const float* __restrict__ g,
                     const float* __restrict__ b, ushort* __restrict__ h){
  int row = blockIdx.x;
  int t = threadIdx.x;
  float4 v = ((const float4*)(x + (size_t)row*D_))[t];
  float s1 = v.x+v.y+v.z+v.w;
  float s2 = v.x*v.x+v.y*v.y+v.z*v.z+v.w*v.w;
  #pragma unroll
  for (int o=1;o<64;o<<=1){ s1 += __shfl_xor(s1,o); s2 += __shfl_xor(s2,o); }
  __shared__ float sm[8];
  int w = t>>6;
  if ((t&63)==0){ sm[w]=s1; sm[4+w]=s2; }
  __syncthreads();
  s1 = sm[0]+sm[1]+sm[2]+sm[3];
  s2 = sm[4]+sm[5]+sm[6]+sm[7];
  float mu = s1 * (1.0f/D_);
  float var = s2 * (1.0f/D_) - mu*mu;
  float rs = rsqrtf(var + 1e-5f);
  float4 gv = ((const float4*)g)[t];
  float4 bv = ((const float4*)b)[t];
  union { ushort u[4]; uint2 p; } o;
  o.u[0] = f2bf((v.x-mu)*rs*gv.x + bv.x);
  o.u[1] = f2bf((v.y-mu)*rs*gv.y + bv.y);
  o.u[2] = f2bf((v.z-mu)*rs*gv.z + bv.z);
  o.u[3] = f2bf((v.w-mu)*rs*gv.w + bv.w);
  ((uint2*)(h + (size_t)row*D_))[t] = o.p;
}

// ---------------- final layernorm (last token per batch) -> fp32 out ----------------
__global__ void k_lnf(const float* __restrict__ x, const float* __restrict__ g,
                      const float* __restrict__ b, float* __restrict__ out){
  int row = blockIdx.x*S_ + (S_-1);
  int t = threadIdx.x;
  float4 v = ((const float4*)(x + (size_t)row*D_))[t];
  float s1 = v.x+v.y+v.z+v.w;
  float s2 = v.x*v.x+v.y*v.y+v.z*v.z+v.w*v.w;
  #pragma unroll
  for (int o=1;o<64;o<<=1){ s1 += __shfl_xor(s1,o); s2 += __shfl_xor(s2,o); }
  __shared__ float sm[8];
  int w = t>>6;
  if ((t&63)==0){ sm[w]=s1; sm[4+w]=s2; }
  __syncthreads();
  s1 = sm[0]+sm[1]+sm[2]+sm[3];
  s2 = sm[4]+sm[5]+sm[6]+sm[7];
  float mu = s1 * (1.0f/D_);
  float var = s2 * (1.0f/D_) - mu*mu;
  float rs = rsqrtf(var + 1e-5f);
  float4 gv = ((const float4*)g)[t];
  float4 bv = ((const float4*)b)[t];
  float4 y;
  y.x = (v.x-mu)*rs*gv.x + bv.x;
  y.y = (v.y-mu)*rs*gv.y + bv.y;
  y.z = (v.z-mu)*rs*gv.z + bv.z;
  y.w = (v.w-mu)*rs*gv.w + bv.w;
  ((float4*)(out + (size_t)blockIdx.x*D_))[t] = y;
}

// ---------------- GEMM: C[m,n] (+)= sum_k A_bf16[m,k] * B_f32[n,k] ----------------
// BM=BN=128, BK=32, 256 threads (4 waves, 2x2), each wave 64x64 via 4x4 MFMA 16x16x32.
// blockIdx.z = mat*kchunks + chunk: mat selects (B,C) pair, chunk selects K-range.
// OP 0: C[+chunk*coff] = acc (split-K partials to disjoint regions, no atomics).
// OP 1: atomicAdd into C (residual += / split-K into live accumulator).
#define LDA 40   // ushort stride: 80B rows -> 16B aligned, ~2-way banks on b128 reads
template<int OP>
__global__ __launch_bounds__(256) void k_gemm_bt(
    const ushort* __restrict__ A,
    const float* __restrict__ B0, const float* __restrict__ B1, const float* __restrict__ B2,
    float* __restrict__ C0, float* __restrict__ C1, float* __restrict__ C2,
    int N, int K, int kchunks, int coff){
  const int z = blockIdx.z;
  const int mat = z / kchunks, chunk = z - mat*kchunks;
  const float* B = (mat==0) ? B0 : ((mat==1) ? B1 : B2);
  float* C = (mat==0) ? C0 : ((mat==1) ? C1 : C2);
  if (OP == 0) C += (size_t)chunk * coff;
  const int Kc = K / kchunks;
  const int kbeg = chunk*Kc, kend = kbeg + Kc;
  const int m0 = blockIdx.x*128, n0 = blockIdx.y*128;
  __shared__ ushort As[128*LDA];
  __shared__ ushort Bs[128*LDA];
  const int t = threadIdx.x;
  const int lane = t & 63, w = t >> 6;
  const int wm = (w & 1)*64, wn = (w >> 1)*64;
  const int fr = lane & 15, fk = (lane >> 4)*8;
  const int trow = t >> 1, tcol = (t & 1)*16;
  const ushort* Ag = A + (size_t)(m0 + trow)*K + tcol;
  const float*  Bg = B + (size_t)(n0 + trow)*K + tcol;
  ushort* Asw = &As[trow*LDA + tcol];
  ushort* Bsw = &Bs[trow*LDA + tcol];

  f32x4 acc[4][4];
  #pragma unroll
  for (int i=0;i<4;i++)
    #pragma unroll
    for (int j=0;j<4;j++)
      #pragma unroll
      for (int r=0;r<4;r++) acc[i][j][r] = 0.0f;

  for (int k0 = kbeg; k0 < kend; k0 += 32){
    uint4 a0 = *(const uint4*)(Ag + k0);
    uint4 a1 = *(const uint4*)(Ag + k0 + 8);
    float4 q0 = *(const float4*)(Bg + k0);
    float4 q1 = *(const float4*)(Bg + k0 + 4);
    float4 q2 = *(const float4*)(Bg + k0 + 8);
    float4 q3 = *(const float4*)(Bg + k0 + 12);
    __syncthreads();   // previous iter's frag reads done
    *(uint4*)(Asw)     = a0;
    *(uint4*)(Asw + 8) = a1;
    *(uint4*)(Bsw)     = pack8(q0, q1);
    *(uint4*)(Bsw + 8) = pack8(q2, q3);
    __syncthreads();
    bf16x8 af[4], bfr[4];
    #pragma unroll
    for (int i=0;i<4;i++) af[i]  = *(const bf16x8*)&As[(wm + i*16 + fr)*LDA + fk];
    #pragma unroll
    for (int j=0;j<4;j++) bfr[j] = *(const bf16x8*)&Bs[(wn + j*16 + fr)*LDA + fk];
    #pragma unroll
    for (int i=0;i<4;i++)
      #pragma unroll
      for (int j=0;j<4;j++)
        acc[i][j] = __builtin_amdgcn_mfma_f32_16x16x32_bf16(af[i], bfr[j], acc[i][j], 0, 0, 0);
  }
  // epilogue: C/D layout col=lane&15, row=(lane>>4)*4+reg
  #pragma unroll
  for (int i=0;i<4;i++){
    int row = m0 + wm + i*16 + (lane >> 4)*4;
    #pragma unroll
    for (int j=0;j<4;j++){
      int col = n0 + wn + j*16 + (lane & 15);
      float* cp = C + (size_t)row*N + col;
      #pragma unroll
      for (int r=0;r<4;r++){
        if (OP == 0) cp[(size_t)r*N] = acc[i][j][r];
        else         atomicAdd(cp + (size_t)r*N, acc[i][j][r]);
      }
    }
  }
}

// ---------------- dual-B W1/W3 GEMM + fused SiLU -> bf16 pb ----------------
// BM=128, BN=64, BK=32; A-staging shared between both B-panels; epilogue computes
// silu(h.w1)*(h.w3) in-register (bit-identical to the old store->silu->load path).
__global__ __launch_bounds__(256) void k_gemm_w13(
    const ushort* __restrict__ A,       // h bf16 [B*S][D]
    const float* __restrict__ W1, const float* __restrict__ W3,
    ushort* __restrict__ P){            // pb bf16 [B*S][F]
  const int m0 = blockIdx.x*128, n0 = blockIdx.y*64;
  __shared__ ushort As [128*LDA];
  __shared__ ushort B1s[64*LDA];
  __shared__ ushort B3s[64*LDA];
  const int t = threadIdx.x;
  const int lane = t & 63, w = t >> 6;
  const int wm = (w & 1)*64, wn = (w >> 1)*32;
  const int fr = lane & 15, fk = (lane >> 4)*8;
  const int trA = t >> 1, tcA = (t & 1)*16;
  const int trB = t >> 2, tcB = (t & 3)*8;
  const ushort* Ag  = A  + (size_t)(m0 + trA)*D_ + tcA;
  const float*  B1g = W1 + (size_t)(n0 + trB)*D_ + tcB;
  const float*  B3g = W3 + (size_t)(n0 + trB)*D_ + tcB;
  ushort* Asw = &As [trA*LDA + tcA];
  ushort* B1w = &B1s[trB*LDA + tcB];
  ushort* B3w = &B3s[trB*LDA + tcB];

  f32x4 a1[4][2], a3[4][2];
  #pragma unroll
  for (int i=0;i<4;i++)
    #pragma unroll
    for (int j=0;j<2;j++)
      #pragma unroll
      for (int r=0;r<4;r++){ a1[i][j][r]=0.f; a3[i][j][r]=0.f; }

  for (int k0 = 0; k0 < D_; k0 += 32){
    uint4 av0 = *(const uint4*)(Ag + k0);
    uint4 av1 = *(const uint4*)(Ag + k0 + 8);
    float4 p0 = *(const float4*)(B1g + k0);
    float4 p1 = *(const float4*)(B1g + k0 + 4);
    float4 r0 = *(const float4*)(B3g + k0);
    float4 r1 = *(const float4*)(B3g + k0 + 4);
    __syncthreads();
    *(uint4*)(Asw)     = av0;
    *(uint4*)(Asw + 8) = av1;
    *(uint4*)(B1w)     = pack8(p0, p1);
    *(uint4*)(B3w)     = pack8(r0, r1);
    __syncthreads();
    bf16x8 af[4], b1f[2], b3f[2];
    #pragma unroll
    for (int i=0;i<4;i++) af[i]  = *(const bf16x8*)&As [(wm + i*16 + fr)*LDA + fk];
    #pragma unroll
    for (int j=0;j<2;j++){
      b1f[j] = *(const bf16x8*)&B1s[(wn + j*16 + fr)*LDA + fk];
      b3f[j] = *(const bf16x8*)&B3s[(wn + j*16 + fr)*LDA + fk];
    }
    #pragma unroll
    for (int i=0;i<4;i++)
      #pragma unroll
      for (int j=0;j<2;j++){
        a1[i][j] = __builtin_amdgcn_mfma_f32_16x16x32_bf16(af[i], b1f[j], a1[i][j], 0, 0, 0);
        a3[i][j] = __builtin_amdgcn_mfma_f32_16x16x32_bf16(af[i], b3f[j], a3[i][j], 0, 0, 0);
      }
  }
  // epilogue: silu(a1)*a3 -> bf16
  #pragma unroll
  for (int i=0;i<4;i++){
    int row = m0 + wm + i*16 + (lane >> 4)*4;
    #pragma unroll
    for (int j=0;j<2;j++){
      int col = n0 + wn + j*16 + (lane & 15);
      #pragma unroll
      for (int r=0;r<4;r++){
        float u = a1[i][j][r];
        float s = u / (1.f + expf(-u)) * a3[i][j][r];
        P[(size_t)(row + r)*F_ + col] = f2bf(s);
      }
    }
  }
}

// ---------------- fused prep: sum QKV partials; RoPE(Q,K) -> bf16; V -> V^T bf16 ----
// blocks [0, 16384): rope on q (first half) / k (second half)
// blocks [16384, 16896): V partial-sum + transpose to [bh][d][S]
__global__ void k_prep(const float* __restrict__ q0, const float* __restrict__ q1,
                       const float* __restrict__ kp0, const float* __restrict__ kp1,
                       const float* __restrict__ v0, const float* __restrict__ v1,
                       ushort* __restrict__ qdst, ushort* __restrict__ kdst,
                       ushort* __restrict__ vt){
  __shared__ float vl[64*68];
  const int half = (B_*S_*D_)/256;   // 8192
  int bx = blockIdx.x;
  int t = threadIdx.x;
  if (bx < 2*half){
    const float *src0, *src1; ushort* dst;
    if (bx < half){ src0 = q0; src1 = q1; dst = qdst; }
    else          { src0 = kp0; src1 = kp1; dst = kdst; bx -= half; }
    int idx = bx*256 + t;
    int d = idx & 63;
    int s = (idx >> 10) & (S_-1);
    float v = src0[idx] + src1[idx];
    float p = __shfl_xor(v, 32);
    float rot = (d < 32) ? -p : p;
    float inv = expf(-(float)(d & 31) * 0.28782313662f);  // ln(10000)/32
    float sn, cs; sincosf((float)s * inv, &sn, &cs);
    dst[idx] = f2bf(v*cs + rot*sn);
    return;
  }
  bx -= 2*half;
  int s0 = (bx & 15)*64, bh = bx >> 4;
  int b = bh >> 4, hh = bh & 15;
  int j = t >> 2, off = (t & 3)*16;
  size_t sidx = ((size_t)(b*S_ + s0 + j))*D_ + hh*64 + off;
  const float* sa = v0 + sidx;
  const float* sb = v1 + sidx;
  #pragma unroll
  for (int q=0; q<4; q++){
    float4 ra = ((const float4*)sa)[q];
    float4 rb = ((const float4*)sb)[q];
    float4 rs; rs.x=ra.x+rb.x; rs.y=ra.y+rb.y; rs.z=ra.z+rb.z; rs.w=ra.w+rb.w;
    *(float4*)&vl[j*68 + off + q*4] = rs;
  }
  __syncthreads();
  int d = t >> 2, so = (t & 3)*16;
  ushort* dst = vt + ((size_t)bh*64 + d)*S_ + s0 + so;
  union { ushort u[8]; uint4 q; } o0, o1;
  #pragma unroll
  for (int jj=0; jj<8; jj++) o0.u[jj] = f2bf(vl[(so + jj)*68 + d]);
  #pragma unroll
  for (int jj=0; jj<8; jj++) o1.u[jj] = f2bf(vl[(so + 8 + jj)*68 + d]);
  *(uint4*)dst       = o0.q;
  *(uint4*)(dst + 8) = o1.q;
}

// ---------------- MFMA flash attention (causal, online softmax) -> bf16 ctx -------
// Block: 64 queries of one (b,h), 4 waves x 16 queries. K/V chunks of 64 in LDS.
// Per wave per chunk: 8 MFMA (QK^T) + online softmax (16-lane reduces) + 8 MFMA (PV).
// Fragment layout (verified in k_gemm_bt): A/B row=lane&15, k=(lane>>4)*8;
//                                          C/D col=lane&15, row=(lane>>4)*4+reg.
#define LDK 72   // ushort stride: 144B rows, 16B aligned, GEMM-class bank pattern
__global__ __launch_bounds__(256) void k_flash(
    const ushort* __restrict__ qh, const ushort* __restrict__ kh,
    const ushort* __restrict__ vt, ushort* __restrict__ ctx){
  __shared__ ushort Kl[64*LDK];      // [key][d]
  __shared__ ushort Vl[64*LDK];      // [d][key]
  __shared__ ushort Pl[4][16*LDK];   // per-wave [q][key]
  const int t = threadIdx.x, lane = t & 63, w = t >> 6;
  const int bh = blockIdx.x, b = bh >> 4, hh = bh & 15;
  // balanced causal schedule: blocks i and i+256 sum to a constant 17 chunks
  const int yy = blockIdx.y;
  const int q0 = 64 * ((yy < 8) ? (15 - 2*yy) : (2*yy - 16));
  const int qw = q0 + w*16;
  const int fr = lane & 15, fk = (lane >> 4)*8;
  bf16x8 qf0, qf1;
  {
    const ushort* qp = qh + ((size_t)(b*S_ + qw + fr))*D_ + hh*64;
    qf0 = *(const bf16x8*)(qp + fk);
    qf1 = *(const bf16x8*)(qp + 32 + fk);
  }
  f32x4 o[4];
  float m[4], l[4];
  #pragma unroll
  for (int r=0;r<4;r++){
    m[r] = -1e30f; l[r] = 0.f;
    #pragma unroll
    for (int j=0;j<4;j++) o[j][r] = 0.f;
  }
  const int nch = q0/64 + 1;
  const int sr = t >> 2, soff = (t & 3)*16;
  ushort* Plw = Pl[w];
  const int rbase = qw + (lane >> 4)*4;
  for (int c=0; c<nch; c++){
    const int k0 = c*64;
    __syncthreads();
    {
      const uint4* ks = (const uint4*)(kh + ((size_t)(b*S_ + k0 + sr))*D_ + hh*64 + soff);
      uint4 ka = ks[0], kb2 = ks[1];
      const uint4* vs = (const uint4*)(vt + ((size_t)(bh*64 + sr))*S_ + k0 + soff);
      uint4 va = vs[0], vb2 = vs[1];
      *(uint4*)&Kl[sr*LDK + soff]     = ka;
      *(uint4*)&Kl[sr*LDK + soff + 8] = kb2;
      *(uint4*)&Vl[sr*LDK + soff]     = va;
      *(uint4*)&Vl[sr*LDK + soff + 8] = vb2;
    }
    __syncthreads();
    // S = Q K^T  (16q x 64k per wave)
    f32x4 sc[4];
    #pragma unroll
    for (int j=0;j<4;j++){
      bf16x8 kf0 = *(const bf16x8*)&Kl[(j*16 + fr)*LDK + fk];
      bf16x8 kf1 = *(const bf16x8*)&Kl[(j*16 + fr)*LDK + 32 + fk];
      f32x4 z; z[0]=0.f; z[1]=0.f; z[2]=0.f; z[3]=0.f;
      z = __builtin_amdgcn_mfma_f32_16x16x32_bf16(qf0, kf0, z, 0, 0, 0);
      sc[j] = __builtin_amdgcn_mfma_f32_16x16x32_bf16(qf1, kf1, z, 0, 0, 0);
    }
    // online softmax per query row (rows live in 16-lane groups)
    #pragma unroll
    for (int r=0;r<4;r++){
      const int qrow = rbase + r;
      float mc = -1e30f;
      #pragma unroll
      for (int j=0;j<4;j++){
        float sv = (k0 + j*16 + fr <= qrow) ? sc[j][r]*0.125f : -1e30f;
        sc[j][r] = sv;
        mc = fmaxf(mc, sv);
      }
      #pragma unroll
      for (int ofs=1; ofs<16; ofs<<=1) mc = fmaxf(mc, __shfl_xor(mc, ofs));
      float mn = fmaxf(m[r], mc);
      float al = expf(m[r] - mn);
      float sum = 0.f;
      #pragma unroll
      for (int j=0;j<4;j++){
        float p = expf(sc[j][r] - mn);
        sum += p;
        Plw[(((lane >> 4)*4) + r)*LDK + j*16 + fr] = f2bf(p);
      }
      #pragma unroll
      for (int ofs=1; ofs<16; ofs<<=1) sum += __shfl_xor(sum, ofs);
      l[r] = l[r]*al + sum;
      m[r] = mn;
      #pragma unroll
      for (int j=0;j<4;j++) o[j][r] *= al;
    }
    // O += P V   (P via wave-private LDS bounce to A-fragment layout; no barrier
    // needed: same-wave LDS RAW is ordered by lgkmcnt)
    bf16x8 pa0 = *(const bf16x8*)&Plw[fr*LDK + fk];
    bf16x8 pa1 = *(const bf16x8*)&Plw[fr*LDK + 32 + fk];
    #pragma unroll
    for (int j=0;j<4;j++){
      bf16x8 vf0 = *(const bf16x8*)&Vl[(j*16 + fr)*LDK + fk];
      bf16x8 vf1 = *(const bf16x8*)&Vl[(j*16 + fr)*LDK + 32 + fk];
      o[j] = __builtin_amdgcn_mfma_f32_16x16x32_bf16(pa0, vf0, o[j], 0, 0, 0);
      o[j] = __builtin_amdgcn_mfma_f32_16x16x32_bf16(pa1, vf1, o[j], 0, 0, 0);
    }
  }
  #pragma unroll
  for (int r=0;r<4;r++){
    float rl = 1.0f / l[r];
    ushort* cp = ctx + ((size_t)(b*S_ + rbase + r))*D_ + hh*64 + fr;
    #pragma unroll
    for (int j=0;j<4;j++) cp[j*16] = f2bf(o[j][r] * rl);
  }
}

extern "C" void kernel_launch(void* const* d_in, const int* in_sizes, int n_in,
                              void* d_out, int out_size, void* d_ws, size_t ws_size,
                              hipStream_t stream) {
  const int*   ids  = (const int*)  d_in[0];
  const float* tok  = (const float*)d_in[1];
  const float* pos  = (const float*)d_in[2];
  const float* wq   = (const float*)d_in[3];
  const float* wk   = (const float*)d_in[4];
  const float* wv   = (const float*)d_in[5];
  const float* wo   = (const float*)d_in[6];
  const float* w1   = (const float*)d_in[7];
  const float* w2   = (const float*)d_in[8];
  const float* w3   = (const float*)d_in[9];
  const float* ln1g = (const float*)d_in[10];
  const float* ln1b = (const float*)d_in[11];
  const float* ln2g = (const float*)d_in[12];
  const float* ln2b = (const float*)d_in[13];
  const float* lnfg = (const float*)d_in[14];
  const float* lnfb = (const float*)d_in[15];

  char* wsb = (char*)d_ws;
  float*  x  = (float*) (wsb);                               // 8 MB
  ushort* h  = (ushort*)(wsb + (size_t)8*1024*1024);         // 4 MB bf16 LN output
  ushort* vt = (ushort*)(wsb + (size_t)12*1024*1024);        // 4 MB bf16 V^T
  ushort* qh = (ushort*)(wsb + (size_t)16*1024*1024);        // 4 MB bf16 Q (post-RoPE)
  ushort* kh = (ushort*)(wsb + (size_t)20*1024*1024);        // 4 MB bf16 K (post-RoPE)
  ushort* cx = (ushort*)(wsb + (size_t)24*1024*1024);        // 4 MB bf16 ctx
  float*  qp = (float*) (wsb + (size_t)48*1024*1024);        // QKV partials: 6 x 8 MB
  ushort* pb = (ushort*)(wsb + (size_t)112*1024*1024);       // 16 MB -> total 128 MB

  // chunk c of matrix m at qp + c*QKV_COFF + m*2M floats
  const int QKV_COFF = 8*1024*1024;                 // floats: 32 MB chunk stride
  float* kp = qp + 2*1024*1024;                     // k partials
  float* vp = qp + 4*1024*1024;                     // v partials

  k_embed<<<B_*S_, 256, 0, stream>>>(ids, tok, pos, x);

  for (int l = 0; l < L_; l++){
    size_t od = (size_t)l*D_*D_;
    size_t fd = (size_t)l*F_*D_;
    k_ln<<<B_*S_, 256, 0, stream>>>(x, ln1g + l*D_, ln1b + l*D_, h);
    // fused Q/K/V, split-K x2 -> 768 blocks, partials to disjoint regions (no atomics)
    k_gemm_bt<0><<<dim3(16, 8, 6), 256, 0, stream>>>(h, wq + od, wk + od, wv + od,
                                                     qp, kp, vp, D_, D_, 2, QKV_COFF);
    // partial-sum + RoPE(Q,K) + V^T in one launch
    k_prep<<<2*(B_*S_*D_)/256 + (S_/64)*B_*H_, 256, 0, stream>>>(
        qp, qp + QKV_COFF, kp, kp + QKV_COFF, vp, vp + QKV_COFF, qh, kh, vt);
    k_flash<<<dim3(B_*H_, S_/64), 256, 0, stream>>>(qh, kh, vt, cx);
    // attn out projection + residual, split-K x4 -> 512 blocks (atomic into live x)
    k_gemm_bt<1><<<dim3(16, 8, 4), 256, 0, stream>>>(cx, wo + od, nullptr, nullptr,
                                                     x, nullptr, nullptr, D_, D_, 4, 0);
    k_ln<<<B_*S_, 256, 0, stream>>>(x, ln2g + l*D_, ln2b + l*D_, h);
    // dual-B W1/W3 + fused SiLU -> pb (bf16), 1024 blocks, no g1/g3 round-trip
    k_gemm_w13<<<dim3(16, 64), 256, 0, stream>>>(h, w1 + fd, w3 + fd, pb);
    // W2 + residual, split-K x8 -> 1024 blocks (atomic into live x)
    k_gemm_bt<1><<<dim3(16, 8, 8), 256, 0, stream>>>(pb, w2 + fd, nullptr, nullptr,
                                                     x, nullptr, nullptr, D_, F_, 8, 0);
  }

  k_lnf<<<B_, 256, 0, stream>>>(x, lnfg, lnfb, (float*)d_out);
}

// Round 6
// 2078.435 us; speedup vs baseline: 2.3606x; 1.0840x over previous
//
#include <hip/hip_runtime.h>
#include <hip/hip_bf16.h>

#define D_ 1024
#define S_ 1024
#define B_ 2
#define H_ 16
#define F_ 4096
#define L_ 6

typedef __bf16 bf16x8 __attribute__((ext_vector_type(8)));
typedef float f32x4 __attribute__((ext_vector_type(4)));

__device__ __forceinline__ unsigned short f2bf(float f){
  union { float f; unsigned u; } v; v.f = f;
  unsigned r = v.u + 0x7fffu + ((v.u >> 16) & 1u);
  return (unsigned short)(r >> 16);
}
__device__ __forceinline__ float bf2f(ushort u){
  union { unsigned u; float f; } v; v.u = ((unsigned)u) << 16; return v.f;
}
__device__ __forceinline__ uint pk2(float lo, float hi){
  return (uint)f2bf(lo) | ((uint)f2bf(hi) << 16);
}
__device__ __forceinline__ uint4 pack8(float4 a, float4 b){
  uint4 r; r.x = pk2(a.x,a.y); r.y = pk2(a.z,a.w); r.z = pk2(b.x,b.y); r.w = pk2(b.z,b.w); return r;
}

// ---------------- embedding ----------------
__global__ void k_embed(const int* __restrict__ ids, const float* __restrict__ tok,
                        const float* __restrict__ pos, float* __restrict__ x){
  int row = blockIdx.x;            // b*S + s
  int s = row & (S_-1);
  int id = ids[row];
  int t = threadIdx.x;
  float4 te = ((const float4*)(tok + (size_t)id*D_))[t];
  float4 pe = ((const float4*)(pos + (size_t)s*D_))[t];
  float4 o; o.x=te.x+pe.x; o.y=te.y+pe.y; o.z=te.z+pe.z; o.w=te.w+pe.w;
  ((float4*)(x + (size_t)row*D_))[t] = o;
}

// ---------------- layernorm -> bf16 ----------------
__global__ void k_ln(const float* __restrict__ x, const float* __restrict__ g,
                     const float* __restrict__ b, ushort* __restrict__ h){
  int row = blockIdx.x;
  int t = threadIdx.x;
  float4 v = ((const float4*)(x + (size_t)row*D_))[t];
  float s1 = v.x+v.y+v.z+v.w;
  float s2 = v.x*v.x+v.y*v.y+v.z*v.z+v.w*v.w;
  #pragma unroll
  for (int o=1;o<64;o<<=1){ s1 += __shfl_xor(s1,o); s2 += __shfl_xor(s2,o); }
  __shared__ float sm[8];
  int w = t>>6;
  if ((t&63)==0){ sm[w]=s1; sm[4+w]=s2; }
  __syncthreads();
  s1 = sm[0]+sm[1]+sm[2]+sm[3];
  s2 = sm[4]+sm[5]+sm[6]+sm[7];
  float mu = s1 * (1.0f/D_);
  float var = s2 * (1.0f/D_) - mu*mu;
  float rs = rsqrtf(var + 1e-5f);
  float4 gv = ((const float4*)g)[t];
  float4 bv = ((const float4*)b)[t];
  union { ushort u[4]; uint2 p; } o;
  o.u[0] = f2bf((v.x-mu)*rs*gv.x + bv.x);
  o.u[1] = f2bf((v.y-mu)*rs*gv.y + bv.y);
  o.u[2] = f2bf((v.z-mu)*rs*gv.z + bv.z);
  o.u[3] = f2bf((v.w-mu)*rs*gv.w + bv.w);
  ((uint2*)(h + (size_t)row*D_))[t] = o.p;
}

// ---------------- final layernorm on compact [2][D] buffer -> fp32 out ----------------
__global__ void k_lnf(const float* __restrict__ xf, const float* __restrict__ g,
                      const float* __restrict__ b, float* __restrict__ out){
  int row = blockIdx.x;            // 0..B_-1
  int t = threadIdx.x;
  float4 v = ((const float4*)(xf + (size_t)row*D_))[t];
  float s1 = v.x+v.y+v.z+v.w;
  float s2 = v.x*v.x+v.y*v.y+v.z*v.z+v.w*v.w;
  #pragma unroll
  for (int o=1;o<64;o<<=1){ s1 += __shfl_xor(s1,o); s2 += __shfl_xor(s2,o); }
  __shared__ float sm[8];
  int w = t>>6;
  if ((t&63)==0){ sm[w]=s1; sm[4+w]=s2; }
  __syncthreads();
  s1 = sm[0]+sm[1]+sm[2]+sm[3];
  s2 = sm[4]+sm[5]+sm[6]+sm[7];
  float mu = s1 * (1.0f/D_);
  float var = s2 * (1.0f/D_) - mu*mu;
  float rs = rsqrtf(var + 1e-5f);
  float4 gv = ((const float4*)g)[t];
  float4 bv = ((const float4*)b)[t];
  float4 y;
  y.x = (v.x-mu)*rs*gv.x + bv.x;
  y.y = (v.y-mu)*rs*gv.y + bv.y;
  y.z = (v.z-mu)*rs*gv.z + bv.z;
  y.w = (v.w-mu)*rs*gv.w + bv.w;
  ((float4*)(out + (size_t)row*D_))[t] = y;
}

// ---------------- GEMM: C[m,n] (+)= sum_k A_bf16[m,k] * B_f32[n,k] ----------------
// BM=BN=128, BK=32, 256 threads (4 waves, 2x2), each wave 64x64 via 4x4 MFMA 16x16x32.
// blockIdx.z = mat*kchunks + chunk: mat selects (B,C) pair, chunk selects K-range.
// OP 0: C[+chunk*coff] = acc (split-K partials to disjoint regions, no atomics).
// OP 1: atomicAdd into C (residual += / split-K into live accumulator).
#define LDA 40   // ushort stride: 80B rows -> 16B aligned, ~2-way banks on b128 reads
template<int OP>
__global__ __launch_bounds__(256) void k_gemm_bt(
    const ushort* __restrict__ A,
    const float* __restrict__ B0, const float* __restrict__ B1, const float* __restrict__ B2,
    float* __restrict__ C0, float* __restrict__ C1, float* __restrict__ C2,
    int N, int K, int kchunks, int coff){
  const int z = blockIdx.z;
  const int mat = z / kchunks, chunk = z - mat*kchunks;
  const float* B = (mat==0) ? B0 : ((mat==1) ? B1 : B2);
  float* C = (mat==0) ? C0 : ((mat==1) ? C1 : C2);
  if (OP == 0) C += (size_t)chunk * coff;
  const int Kc = K / kchunks;
  const int kbeg = chunk*Kc, kend = kbeg + Kc;
  const int m0 = blockIdx.x*128, n0 = blockIdx.y*128;
  __shared__ ushort As[128*LDA];
  __shared__ ushort Bs[128*LDA];
  const int t = threadIdx.x;
  const int lane = t & 63, w = t >> 6;
  const int wm = (w & 1)*64, wn = (w >> 1)*64;
  const int fr = lane & 15, fk = (lane >> 4)*8;
  const int trow = t >> 1, tcol = (t & 1)*16;
  const ushort* Ag = A + (size_t)(m0 + trow)*K + tcol;
  const float*  Bg = B + (size_t)(n0 + trow)*K + tcol;
  ushort* Asw = &As[trow*LDA + tcol];
  ushort* Bsw = &Bs[trow*LDA + tcol];

  f32x4 acc[4][4];
  #pragma unroll
  for (int i=0;i<4;i++)
    #pragma unroll
    for (int j=0;j<4;j++)
      #pragma unroll
      for (int r=0;r<4;r++) acc[i][j][r] = 0.0f;

  for (int k0 = kbeg; k0 < kend; k0 += 32){
    uint4 a0 = *(const uint4*)(Ag + k0);
    uint4 a1 = *(const uint4*)(Ag + k0 + 8);
    float4 q0 = *(const float4*)(Bg + k0);
    float4 q1 = *(const float4*)(Bg + k0 + 4);
    float4 q2 = *(const float4*)(Bg + k0 + 8);
    float4 q3 = *(const float4*)(Bg + k0 + 12);
    __syncthreads();   // previous iter's frag reads done
    *(uint4*)(Asw)     = a0;
    *(uint4*)(Asw + 8) = a1;
    *(uint4*)(Bsw)     = pack8(q0, q1);
    *(uint4*)(Bsw + 8) = pack8(q2, q3);
    __syncthreads();
    bf16x8 af[4], bfr[4];
    #pragma unroll
    for (int i=0;i<4;i++) af[i]  = *(const bf16x8*)&As[(wm + i*16 + fr)*LDA + fk];
    #pragma unroll
    for (int j=0;j<4;j++) bfr[j] = *(const bf16x8*)&Bs[(wn + j*16 + fr)*LDA + fk];
    #pragma unroll
    for (int i=0;i<4;i++)
      #pragma unroll
      for (int j=0;j<4;j++)
        acc[i][j] = __builtin_amdgcn_mfma_f32_16x16x32_bf16(af[i], bfr[j], acc[i][j], 0, 0, 0);
  }
  // epilogue: C/D layout col=lane&15, row=(lane>>4)*4+reg
  #pragma unroll
  for (int i=0;i<4;i++){
    int row = m0 + wm + i*16 + (lane >> 4)*4;
    #pragma unroll
    for (int j=0;j<4;j++){
      int col = n0 + wn + j*16 + (lane & 15);
      float* cp = C + (size_t)row*N + col;
      #pragma unroll
      for (int r=0;r<4;r++){
        if (OP == 0) cp[(size_t)r*N] = acc[i][j][r];
        else         atomicAdd(cp + (size_t)r*N, acc[i][j][r]);
      }
    }
  }
}

// ---------------- dual-B W1/W3 GEMM + fused SiLU -> bf16 pb ----------------
__global__ __launch_bounds__(256) void k_gemm_w13(
    const ushort* __restrict__ A,       // h bf16 [B*S][D]
    const float* __restrict__ W1, const float* __restrict__ W3,
    ushort* __restrict__ P){            // pb bf16 [B*S][F]
  const int m0 = blockIdx.x*128, n0 = blockIdx.y*64;
  __shared__ ushort As [128*LDA];
  __shared__ ushort B1s[64*LDA];
  __shared__ ushort B3s[64*LDA];
  const int t = threadIdx.x;
  const int lane = t & 63, w = t >> 6;
  const int wm = (w & 1)*64, wn = (w >> 1)*32;
  const int fr = lane & 15, fk = (lane >> 4)*8;
  const int trA = t >> 1, tcA = (t & 1)*16;
  const int trB = t >> 2, tcB = (t & 3)*8;
  const ushort* Ag  = A  + (size_t)(m0 + trA)*D_ + tcA;
  const float*  B1g = W1 + (size_t)(n0 + trB)*D_ + tcB;
  const float*  B3g = W3 + (size_t)(n0 + trB)*D_ + tcB;
  ushort* Asw = &As [trA*LDA + tcA];
  ushort* B1w = &B1s[trB*LDA + tcB];
  ushort* B3w = &B3s[trB*LDA + tcB];

  f32x4 a1[4][2], a3[4][2];
  #pragma unroll
  for (int i=0;i<4;i++)
    #pragma unroll
    for (int j=0;j<2;j++)
      #pragma unroll
      for (int r=0;r<4;r++){ a1[i][j][r]=0.f; a3[i][j][r]=0.f; }

  for (int k0 = 0; k0 < D_; k0 += 32){
    uint4 av0 = *(const uint4*)(Ag + k0);
    uint4 av1 = *(const uint4*)(Ag + k0 + 8);
    float4 p0 = *(const float4*)(B1g + k0);
    float4 p1 = *(const float4*)(B1g + k0 + 4);
    float4 r0 = *(const float4*)(B3g + k0);
    float4 r1 = *(const float4*)(B3g + k0 + 4);
    __syncthreads();
    *(uint4*)(Asw)     = av0;
    *(uint4*)(Asw + 8) = av1;
    *(uint4*)(B1w)     = pack8(p0, p1);
    *(uint4*)(B3w)     = pack8(r0, r1);
    __syncthreads();
    bf16x8 af[4], b1f[2], b3f[2];
    #pragma unroll
    for (int i=0;i<4;i++) af[i]  = *(const bf16x8*)&As [(wm + i*16 + fr)*LDA + fk];
    #pragma unroll
    for (int j=0;j<2;j++){
      b1f[j] = *(const bf16x8*)&B1s[(wn + j*16 + fr)*LDA + fk];
      b3f[j] = *(const bf16x8*)&B3s[(wn + j*16 + fr)*LDA + fk];
    }
    #pragma unroll
    for (int i=0;i<4;i++)
      #pragma unroll
      for (int j=0;j<2;j++){
        a1[i][j] = __builtin_amdgcn_mfma_f32_16x16x32_bf16(af[i], b1f[j], a1[i][j], 0, 0, 0);
        a3[i][j] = __builtin_amdgcn_mfma_f32_16x16x32_bf16(af[i], b3f[j], a3[i][j], 0, 0, 0);
      }
  }
  #pragma unroll
  for (int i=0;i<4;i++){
    int row = m0 + wm + i*16 + (lane >> 4)*4;
    #pragma unroll
    for (int j=0;j<2;j++){
      int col = n0 + wn + j*16 + (lane & 15);
      #pragma unroll
      for (int r=0;r<4;r++){
        float u = a1[i][j][r];
        float s = u / (1.f + expf(-u)) * a3[i][j][r];
        P[(size_t)(row + r)*F_ + col] = f2bf(s);
      }
    }
  }
}

// ---------------- fused prep: sum QKV partials; RoPE(Q,K) -> bf16; V -> V^T bf16 ----
// mode 0: blocks [0,half)=Q rope, [half,2half)=K rope, rest=V transpose
// mode 1 (last layer): blocks [0,half)=K rope, rest=V transpose (no Q)
__global__ void k_prep(const float* __restrict__ q0, const float* __restrict__ q1,
                       const float* __restrict__ kp0, const float* __restrict__ kp1,
                       const float* __restrict__ v0, const float* __restrict__ v1,
                       ushort* __restrict__ qdst, ushort* __restrict__ kdst,
                       ushort* __restrict__ vt, int mode){
  __shared__ float vl[64*68];
  const int half = (B_*S_*D_)/256;   // 8192
  int bx = blockIdx.x;
  int t = threadIdx.x;
  const int nrope = (mode == 0) ? 2*half : half;
  if (bx < nrope){
    const float *src0, *src1; ushort* dst;
    if (mode == 0 && bx < half){ src0 = q0; src1 = q1; dst = qdst; }
    else { src0 = kp0; src1 = kp1; dst = kdst; if (mode == 0) bx -= half; }
    int idx = bx*256 + t;
    int d = idx & 63;
    int s = (idx >> 10) & (S_-1);
    float v = src0[idx] + src1[idx];
    float p = __shfl_xor(v, 32);
    float rot = (d < 32) ? -p : p;
    float inv = expf(-(float)(d & 31) * 0.28782313662f);  // ln(10000)/32
    float sn, cs; sincosf((float)s * inv, &sn, &cs);
    dst[idx] = f2bf(v*cs + rot*sn);
    return;
  }
  bx -= nrope;
  int s0 = (bx & 15)*64, bh = bx >> 4;
  int b = bh >> 4, hh = bh & 15;
  int j = t >> 2, off = (t & 3)*16;
  size_t sidx = ((size_t)(b*S_ + s0 + j))*D_ + hh*64 + off;
  const float* sa = v0 + sidx;
  const float* sb = v1 + sidx;
  #pragma unroll
  for (int q=0; q<4; q++){
    float4 ra = ((const float4*)sa)[q];
    float4 rb = ((const float4*)sb)[q];
    float4 rs; rs.x=ra.x+rb.x; rs.y=ra.y+rb.y; rs.z=ra.z+rb.z; rs.w=ra.w+rb.w;
    *(float4*)&vl[j*68 + off + q*4] = rs;
  }
  __syncthreads();
  int d = t >> 2, so = (t & 3)*16;
  ushort* dst = vt + ((size_t)bh*64 + d)*S_ + s0 + so;
  union { ushort u[8]; uint4 q; } o0, o1;
  #pragma unroll
  for (int jj=0; jj<8; jj++) o0.u[jj] = f2bf(vl[(so + jj)*68 + d]);
  #pragma unroll
  for (int jj=0; jj<8; jj++) o1.u[jj] = f2bf(vl[(so + 8 + jj)*68 + d]);
  *(uint4*)dst       = o0.q;
  *(uint4*)(dst + 8) = o1.q;
}

// ---------------- MFMA flash attention (causal, online softmax) -> bf16 ctx -------
#define LDK 72
__global__ __launch_bounds__(256) void k_flash(
    const ushort* __restrict__ qh, const ushort* __restrict__ kh,
    const ushort* __restrict__ vt, ushort* __restrict__ ctx){
  __shared__ ushort Kl[64*LDK];      // [key][d]
  __shared__ ushort Vl[64*LDK];      // [d][key]
  __shared__ ushort Pl[4][16*LDK];   // per-wave [q][key]
  const int t = threadIdx.x, lane = t & 63, w = t >> 6;
  const int bh = blockIdx.x, b = bh >> 4, hh = bh & 15;
  const int yy = blockIdx.y;
  const int q0 = 64 * ((yy < 8) ? (15 - 2*yy) : (2*yy - 16));
  const int qw = q0 + w*16;
  const int fr = lane & 15, fk = (lane >> 4)*8;
  bf16x8 qf0, qf1;
  {
    const ushort* qp = qh + ((size_t)(b*S_ + qw + fr))*D_ + hh*64;
    qf0 = *(const bf16x8*)(qp + fk);
    qf1 = *(const bf16x8*)(qp + 32 + fk);
  }
  f32x4 o[4];
  float m[4], l[4];
  #pragma unroll
  for (int r=0;r<4;r++){
    m[r] = -1e30f; l[r] = 0.f;
    #pragma unroll
    for (int j=0;j<4;j++) o[j][r] = 0.f;
  }
  const int nch = q0/64 + 1;
  const int sr = t >> 2, soff = (t & 3)*16;
  ushort* Plw = Pl[w];
  const int rbase = qw + (lane >> 4)*4;
  for (int c=0; c<nch; c++){
    const int k0 = c*64;
    __syncthreads();
    {
      const uint4* ks = (const uint4*)(kh + ((size_t)(b*S_ + k0 + sr))*D_ + hh*64 + soff);
      uint4 ka = ks[0], kb2 = ks[1];
      const uint4* vs = (const uint4*)(vt + ((size_t)(bh*64 + sr))*S_ + k0 + soff);
      uint4 va = vs[0], vb2 = vs[1];
      *(uint4*)&Kl[sr*LDK + soff]     = ka;
      *(uint4*)&Kl[sr*LDK + soff + 8] = kb2;
      *(uint4*)&Vl[sr*LDK + soff]     = va;
      *(uint4*)&Vl[sr*LDK + soff + 8] = vb2;
    }
    __syncthreads();
    f32x4 sc[4];
    #pragma unroll
    for (int j=0;j<4;j++){
      bf16x8 kf0 = *(const bf16x8*)&Kl[(j*16 + fr)*LDK + fk];
      bf16x8 kf1 = *(const bf16x8*)&Kl[(j*16 + fr)*LDK + 32 + fk];
      f32x4 z; z[0]=0.f; z[1]=0.f; z[2]=0.f; z[3]=0.f;
      z = __builtin_amdgcn_mfma_f32_16x16x32_bf16(qf0, kf0, z, 0, 0, 0);
      sc[j] = __builtin_amdgcn_mfma_f32_16x16x32_bf16(qf1, kf1, z, 0, 0, 0);
    }
    #pragma unroll
    for (int r=0;r<4;r++){
      const int qrow = rbase + r;
      float mc = -1e30f;
      #pragma unroll
      for (int j=0;j<4;j++){
        float sv = (k0 + j*16 + fr <= qrow) ? sc[j][r]*0.125f : -1e30f;
        sc[j][r] = sv;
        mc = fmaxf(mc, sv);
      }
      #pragma unroll
      for (int ofs=1; ofs<16; ofs<<=1) mc = fmaxf(mc, __shfl_xor(mc, ofs));
      float mn = fmaxf(m[r], mc);
      float al = expf(m[r] - mn);
      float sum = 0.f;
      #pragma unroll
      for (int j=0;j<4;j++){
        float p = expf(sc[j][r] - mn);
        sum += p;
        Plw[(((lane >> 4)*4) + r)*LDK + j*16 + fr] = f2bf(p);
      }
      #pragma unroll
      for (int ofs=1; ofs<16; ofs<<=1) sum += __shfl_xor(sum, ofs);
      l[r] = l[r]*al + sum;
      m[r] = mn;
      #pragma unroll
      for (int j=0;j<4;j++) o[j][r] *= al;
    }
    bf16x8 pa0 = *(const bf16x8*)&Plw[fr*LDK + fk];
    bf16x8 pa1 = *(const bf16x8*)&Plw[fr*LDK + 32 + fk];
    #pragma unroll
    for (int j=0;j<4;j++){
      bf16x8 vf0 = *(const bf16x8*)&Vl[(j*16 + fr)*LDK + fk];
      bf16x8 vf1 = *(const bf16x8*)&Vl[(j*16 + fr)*LDK + 32 + fk];
      o[j] = __builtin_amdgcn_mfma_f32_16x16x32_bf16(pa0, vf0, o[j], 0, 0, 0);
      o[j] = __builtin_amdgcn_mfma_f32_16x16x32_bf16(pa1, vf1, o[j], 0, 0, 0);
    }
  }
  #pragma unroll
  for (int r=0;r<4;r++){
    float rl = 1.0f / l[r];
    ushort* cp = ctx + ((size_t)(b*S_ + rbase + r))*D_ + hh*64 + fr;
    #pragma unroll
    for (int j=0;j<4;j++) cp[j*16] = f2bf(o[j][r] * rl);
  }
}

// ---------------- 2-row skinny GEMM: C[2][N] = (add?) + A2_bf16 . B_f32^T ----------
// 16 cols/block, 16 lanes per col split K; A rows staged in LDS.
__global__ __launch_bounds__(256) void k_row1(
    const ushort* __restrict__ A0, const ushort* __restrict__ A1,
    const float* __restrict__ B, int K,
    const float* __restrict__ add0, const float* __restrict__ add1,
    float* __restrict__ C, int N){
  __shared__ ushort As[2*4096];
  const int t = threadIdx.x;
  const int nv = 2*K/8;
  for (int i = t; i < nv; i += 256){
    int row = (i*8 >= K) ? 1 : 0;
    int off = i*8 - row*K;
    ((uint4*)As)[i] = *(const uint4*)((row ? A1 : A0) + off);
  }
  __syncthreads();
  const int col = blockIdx.x*16 + (t >> 4);
  const int p = t & 15;
  const float* Bp = B + (size_t)col*K;
  float acc0 = 0.f, acc1 = 0.f;
  for (int i = 0; i < K/64; i++){
    int k = p*4 + i*64;
    float4 bv = *(const float4*)(Bp + k);
    ushort4 u0 = *(const ushort4*)&As[k];
    ushort4 u1 = *(const ushort4*)&As[K + k];
    acc0 += bv.x*bf2f(u0.x) + bv.y*bf2f(u0.y) + bv.z*bf2f(u0.z) + bv.w*bf2f(u0.w);
    acc1 += bv.x*bf2f(u1.x) + bv.y*bf2f(u1.y) + bv.z*bf2f(u1.z) + bv.w*bf2f(u1.w);
  }
  #pragma unroll
  for (int ofs=1; ofs<16; ofs<<=1){ acc0 += __shfl_xor(acc0, ofs); acc1 += __shfl_xor(acc1, ofs); }
  if (p == 0){
    C[col]     = (add0 ? add0[col] : 0.f) + acc0;
    C[N + col] = (add1 ? add1[col] : 0.f) + acc1;
  }
}

// ---------------- 2-row dual-B GEMM + SiLU: pl[2][F] = silu(h2.w1)*(h2.w3) ----------
__global__ __launch_bounds__(256) void k_row13(
    const ushort* __restrict__ H2,      // [2][D] bf16 compact
    const float* __restrict__ W1, const float* __restrict__ W3,
    ushort* __restrict__ P){            // [2][F]
  __shared__ ushort As[2*1024];
  const int t = threadIdx.x;
  ((uint4*)As)[t] = *(const uint4*)(H2 + t*8);
  __syncthreads();
  const int col = blockIdx.x*16 + (t >> 4);
  const int p = t & 15;
  const float* b1 = W1 + (size_t)col*D_;
  const float* b3 = W3 + (size_t)col*D_;
  float u10=0.f, u11=0.f, u30=0.f, u31=0.f;
  for (int i = 0; i < D_/64; i++){
    int k = p*4 + i*64;
    float4 v1 = *(const float4*)(b1 + k);
    float4 v3 = *(const float4*)(b3 + k);
    ushort4 a0 = *(const ushort4*)&As[k];
    ushort4 a1 = *(const ushort4*)&As[D_ + k];
    float f00=bf2f(a0.x), f01=bf2f(a0.y), f02=bf2f(a0.z), f03=bf2f(a0.w);
    float f10=bf2f(a1.x), f11=bf2f(a1.y), f12=bf2f(a1.z), f13=bf2f(a1.w);
    u10 += v1.x*f00 + v1.y*f01 + v1.z*f02 + v1.w*f03;
    u11 += v1.x*f10 + v1.y*f11 + v1.z*f12 + v1.w*f13;
    u30 += v3.x*f00 + v3.y*f01 + v3.z*f02 + v3.w*f03;
    u31 += v3.x*f10 + v3.y*f11 + v3.z*f12 + v3.w*f13;
  }
  #pragma unroll
  for (int ofs=1; ofs<16; ofs<<=1){
    u10 += __shfl_xor(u10, ofs); u11 += __shfl_xor(u11, ofs);
    u30 += __shfl_xor(u30, ofs); u31 += __shfl_xor(u31, ofs);
  }
  if (p == 0){
    P[col]      = f2bf(u10 / (1.f + expf(-u10)) * u30);
    P[F_ + col] = f2bf(u11 / (1.f + expf(-u11)) * u31);
  }
}

// ---------------- decode attention: 1 query (last token) per (b,h) ----------------
// grid 32 = b*16+h. Applies RoPE to q in LDS (s = S-1). No causal mask needed.
__global__ __launch_bounds__(256) void k_dec(
    const float* __restrict__ q2,       // [2][D] pre-RoPE fp32
    const ushort* __restrict__ kh,      // [b,s,h,d] bf16 (RoPE'd)
    const ushort* __restrict__ vt,      // [bh][d][S] bf16
    ushort* __restrict__ c2){           // [2][D] bf16 ctx
  __shared__ float qs[64];
  __shared__ float ps[S_];
  __shared__ float red[8];
  const int t = threadIdx.x, lane = t & 63, w = t >> 6;
  const int bh = blockIdx.x, b = bh >> 4, hh = bh & 15;
  if (t < 64){
    int d = t;
    float v = q2[b*D_ + hh*64 + d];
    float pr = q2[b*D_ + hh*64 + (d ^ 32)];
    float rot = (d < 32) ? -pr : pr;
    float inv = expf(-(float)(d & 31) * 0.28782313662f);
    float sn, cs; sincosf((float)(S_-1) * inv, &sn, &cs);
    qs[d] = v*cs + rot*sn;
  }
  __syncthreads();
  // scores: 4 keys per thread
  float sc[4];
  #pragma unroll
  for (int j=0;j<4;j++){
    int key = t + j*256;
    const uint4* kp = (const uint4*)(kh + ((size_t)(b*S_ + key))*D_ + hh*64);
    float acc = 0.f;
    #pragma unroll
    for (int i=0;i<8;i++){
      uint4 kv = kp[i];
      const ushort* ku = (const ushort*)&kv;
      #pragma unroll
      for (int jj=0;jj<8;jj++) acc += qs[i*8+jj] * bf2f(ku[jj]);
    }
    sc[j] = acc * 0.125f;
  }
  float mx = fmaxf(fmaxf(sc[0],sc[1]), fmaxf(sc[2],sc[3]));
  #pragma unroll
  for (int ofs=1; ofs<64; ofs<<=1) mx = fmaxf(mx, __shfl_xor(mx, ofs));
  if (lane == 0) red[w] = mx;
  __syncthreads();
  mx = fmaxf(fmaxf(red[0],red[1]), fmaxf(red[2],red[3]));
  float ls = 0.f;
  #pragma unroll
  for (int j=0;j<4;j++){
    float pv = expf(sc[j] - mx);
    ps[t + j*256] = pv;
    ls += pv;
  }
  #pragma unroll
  for (int ofs=1; ofs<64; ofs<<=1) ls += __shfl_xor(ls, ofs);
  if (lane == 0) red[4 + w] = ls;
  __syncthreads();
  const float L = red[4]+red[5]+red[6]+red[7];
  // PV: d = t>>2, quarter of keys per lane
  const int d = t >> 2, part = t & 3;
  const uint4* vp = (const uint4*)(vt + ((size_t)(bh*64 + d))*S_ + part*256);
  float acc = 0.f;
  for (int i=0;i<32;i++){
    uint4 vv = vp[i];
    const ushort* vu = (const ushort*)&vv;
    #pragma unroll
    for (int jj=0;jj<8;jj++) acc += ps[part*256 + i*8 + jj] * bf2f(vu[jj]);
  }
  acc += __shfl_xor(acc, 1);
  acc += __shfl_xor(acc, 2);
  if (part == 0) c2[b*D_ + hh*64 + d] = f2bf(acc / L);
}

extern "C" void kernel_launch(void* const* d_in, const int* in_sizes, int n_in,
                              void* d_out, int out_size, void* d_ws, size_t ws_size,
                              hipStream_t stream) {
  const int*   ids  = (const int*)  d_in[0];
  const float* tok  = (const float*)d_in[1];
  const float* pos  = (const float*)d_in[2];
  const float* wq   = (const float*)d_in[3];
  const float* wk   = (const float*)d_in[4];
  const float* wv   = (const float*)d_in[5];
  const float* wo   = (const float*)d_in[6];
  const float* w1   = (const float*)d_in[7];
  const float* w2   = (const float*)d_in[8];
  const float* w3   = (const float*)d_in[9];
  const float* ln1g = (const float*)d_in[10];
  const float* ln1b = (const float*)d_in[11];
  const float* ln2g = (const float*)d_in[12];
  const float* ln2b = (const float*)d_in[13];
  const float* lnfg = (const float*)d_in[14];
  const float* lnfb = (const float*)d_in[15];

  char* wsb = (char*)d_ws;
  float*  x  = (float*) (wsb);                               // 8 MB
  ushort* h  = (ushort*)(wsb + (size_t)8*1024*1024);         // 4 MB bf16 LN output
  ushort* vt = (ushort*)(wsb + (size_t)12*1024*1024);        // 4 MB bf16 V^T
  ushort* qh = (ushort*)(wsb + (size_t)16*1024*1024);        // 4 MB bf16 Q (post-RoPE)
  ushort* kh = (ushort*)(wsb + (size_t)20*1024*1024);        // 4 MB bf16 K (post-RoPE)
  ushort* cx = (ushort*)(wsb + (size_t)24*1024*1024);        // 4 MB bf16 ctx
  // last-layer skinny buffers (28 MB region)
  float*  q2 = (float*) (wsb + (size_t)28*1024*1024);        // [2][1024] fp32
  ushort* c2 = (ushort*)(wsb + (size_t)28*1024*1024 + 8192); // [2][1024] bf16
  float*  xl = (float*) (wsb + (size_t)28*1024*1024 + 16384);// [2][1024] fp32
  ushort* h2 = (ushort*)(wsb + (size_t)28*1024*1024 + 24576);// [2][1024] bf16
  ushort* pl = (ushort*)(wsb + (size_t)28*1024*1024 + 32768);// [2][4096] bf16
  float*  xf = (float*) (wsb + (size_t)28*1024*1024 + 49152);// [2][1024] fp32
  float*  qp = (float*) (wsb + (size_t)48*1024*1024);        // QKV partials: 6 x 8 MB
  ushort* pb = (ushort*)(wsb + (size_t)112*1024*1024);       // 16 MB -> total 128 MB

  const int QKV_COFF = 8*1024*1024;                 // floats: 32 MB chunk stride
  float* kp = qp + 2*1024*1024;                     // k partials
  float* vp = qp + 4*1024*1024;                     // v partials

  k_embed<<<B_*S_, 256, 0, stream>>>(ids, tok, pos, x);

  for (int l = 0; l < L_; l++){
    size_t od = (size_t)l*D_*D_;
    size_t fd = (size_t)l*F_*D_;
    if (l < L_-1){
      k_ln<<<B_*S_, 256, 0, stream>>>(x, ln1g + l*D_, ln1b + l*D_, h);
      k_gemm_bt<0><<<dim3(16, 8, 6), 256, 0, stream>>>(h, wq + od, wk + od, wv + od,
                                                       qp, kp, vp, D_, D_, 2, QKV_COFF);
      k_prep<<<2*(B_*S_*D_)/256 + (S_/64)*B_*H_, 256, 0, stream>>>(
          qp, qp + QKV_COFF, kp, kp + QKV_COFF, vp, vp + QKV_COFF, qh, kh, vt, 0);
      k_flash<<<dim3(B_*H_, S_/64), 256, 0, stream>>>(qh, kh, vt, cx);
      k_gemm_bt<1><<<dim3(16, 8, 4), 256, 0, stream>>>(cx, wo + od, nullptr, nullptr,
                                                       x, nullptr, nullptr, D_, D_, 4, 0);
      k_ln<<<B_*S_, 256, 0, stream>>>(x, ln2g + l*D_, ln2b + l*D_, h);
      k_gemm_w13<<<dim3(16, 64), 256, 0, stream>>>(h, w1 + fd, w3 + fd, pb);
      k_gemm_bt<1><<<dim3(16, 8, 8), 256, 0, stream>>>(pb, w2 + fd, nullptr, nullptr,
                                                       x, nullptr, nullptr, D_, F_, 8, 0);
    } else {
      // last layer: only the final token per batch matters downstream.
      k_ln<<<B_*S_, 256, 0, stream>>>(x, ln1g + l*D_, ln1b + l*D_, h);
      // K,V projections (all rows), split-K x2 -> 512 blocks
      k_gemm_bt<0><<<dim3(16, 8, 4), 256, 0, stream>>>(h, wk + od, wv + od, nullptr,
                                                       kp, vp, nullptr, D_, D_, 2, QKV_COFF);
      // K rope + V transpose only
      k_prep<<<(B_*S_*D_)/256 + (S_/64)*B_*H_, 256, 0, stream>>>(
          nullptr, nullptr, kp, kp + QKV_COFF, vp, vp + QKV_COFF, qh, kh, vt, 1);
      // Q for the 2 last rows (pre-rope; rope applied inside k_dec)
      k_row1<<<64, 256, 0, stream>>>(h + (size_t)(S_-1)*D_, h + (size_t)(B_*S_-1)*D_,
                                     wq + od, D_, nullptr, nullptr, q2, D_);
      k_dec<<<B_*H_, 256, 0, stream>>>(q2, kh, vt, c2);
      // wo projection + residual for 2 rows -> xl
      k_row1<<<64, 256, 0, stream>>>(c2, c2 + D_, wo + od, D_,
                                     x + (size_t)(S_-1)*D_, x + (size_t)(B_*S_-1)*D_, xl, D_);
      k_ln<<<2, 256, 0, stream>>>(xl, ln2g + l*D_, ln2b + l*D_, h2);
      k_row13<<<F_/16, 256, 0, stream>>>(h2, w1 + fd, w3 + fd, pl);
      k_row1<<<64, 256, 0, stream>>>(pl, pl + F_, w2 + fd, F_, xl, xl + D_, xf, D_);
    }
  }

  k_lnf<<<B_, 256, 0, stream>>>(xf, lnfg, lnfb, (float*)d_out);
}

// Round 7
// 1801.414 us; speedup vs baseline: 2.7237x; 1.1538x over previous
//
#include <hip/hip_runtime.h>
#include <hip/hip_bf16.h>

#define D_ 1024
#define S_ 1024
#define B_ 2
#define H_ 16
#define F_ 4096
#define L_ 6

typedef __bf16 bf16x8 __attribute__((ext_vector_type(8)));
typedef float f32x4 __attribute__((ext_vector_type(4)));

__device__ __forceinline__ unsigned short f2bf(float f){
  union { float f; unsigned u; } v; v.f = f;
  unsigned r = v.u + 0x7fffu + ((v.u >> 16) & 1u);
  return (unsigned short)(r >> 16);
}
__device__ __forceinline__ float bf2f(ushort u){
  union { unsigned u; float f; } v; v.u = ((unsigned)u) << 16; return v.f;
}
__device__ __forceinline__ uint pk2(float lo, float hi){
  return (uint)f2bf(lo) | ((uint)f2bf(hi) << 16);
}
__device__ __forceinline__ uint4 pack8(float4 a, float4 b){
  uint4 r; r.x = pk2(a.x,a.y); r.y = pk2(a.z,a.w); r.z = pk2(b.x,b.y); r.w = pk2(b.z,b.w); return r;
}

// ---------------- embedding ----------------
__global__ void k_embed(const int* __restrict__ ids, const float* __restrict__ tok,
                        const float* __restrict__ pos, float* __restrict__ x){
  int row = blockIdx.x;            // b*S + s
  int s = row & (S_-1);
  int id = ids[row];
  int t = threadIdx.x;
  float4 te = ((const float4*)(tok + (size_t)id*D_))[t];
  float4 pe = ((const float4*)(pos + (size_t)s*D_))[t];
  float4 o; o.x=te.x+pe.x; o.y=te.y+pe.y; o.z=te.z+pe.z; o.w=te.w+pe.w;
  ((float4*)(x + (size_t)row*D_))[t] = o;
}

// ---------------- layernorm -> bf16 ----------------
__global__ void k_ln(const float* __restrict__ x, const float* __restrict__ g,
                     const float* __restrict__ b, ushort* __restrict__ h){
  int row = blockIdx.x;
  int t = threadIdx.x;
  float4 v = ((const float4*)(x + (size_t)row*D_))[t];
  float s1 = v.x+v.y+v.z+v.w;
  float s2 = v.x*v.x+v.y*v.y+v.z*v.z+v.w*v.w;
  #pragma unroll
  for (int o=1;o<64;o<<=1){ s1 += __shfl_xor(s1,o); s2 += __shfl_xor(s2,o); }
  __shared__ float sm[8];
  int w = t>>6;
  if ((t&63)==0){ sm[w]=s1; sm[4+w]=s2; }
  __syncthreads();
  s1 = sm[0]+sm[1]+sm[2]+sm[3];
  s2 = sm[4]+sm[5]+sm[6]+sm[7];
  float mu = s1 * (1.0f/D_);
  float var = s2 * (1.0f/D_) - mu*mu;
  float rs = rsqrtf(var + 1e-5f);
  float4 gv = ((const float4*)g)[t];
  float4 bv = ((const float4*)b)[t];
  union { ushort u[4]; uint2 p; } o;
  o.u[0] = f2bf((v.x-mu)*rs*gv.x + bv.x);
  o.u[1] = f2bf((v.y-mu)*rs*gv.y + bv.y);
  o.u[2] = f2bf((v.z-mu)*rs*gv.z + bv.z);
  o.u[3] = f2bf((v.w-mu)*rs*gv.w + bv.w);
  ((uint2*)(h + (size_t)row*D_))[t] = o.p;
}

// ---------------- fused: x += sum(partials); h = LN(x) -> bf16 ----------------
// Replaces {split-K atomic accumulate + separate k_ln}. Deterministic, atomic-free.
__global__ void k_red_ln(const float* __restrict__ part, int nchunks, int coff,
                         float* __restrict__ x, const float* __restrict__ g,
                         const float* __restrict__ b, ushort* __restrict__ h){
  int row = blockIdx.x;
  int t = threadIdx.x;
  float4 v = ((const float4*)(x + (size_t)row*D_))[t];
  for (int c = 0; c < nchunks; c++){
    float4 p = ((const float4*)(part + (size_t)c*coff + (size_t)row*D_))[t];
    v.x += p.x; v.y += p.y; v.z += p.z; v.w += p.w;
  }
  ((float4*)(x + (size_t)row*D_))[t] = v;
  float s1 = v.x+v.y+v.z+v.w;
  float s2 = v.x*v.x+v.y*v.y+v.z*v.z+v.w*v.w;
  #pragma unroll
  for (int o=1;o<64;o<<=1){ s1 += __shfl_xor(s1,o); s2 += __shfl_xor(s2,o); }
  __shared__ float sm[8];
  int w = t>>6;
  if ((t&63)==0){ sm[w]=s1; sm[4+w]=s2; }
  __syncthreads();
  s1 = sm[0]+sm[1]+sm[2]+sm[3];
  s2 = sm[4]+sm[5]+sm[6]+sm[7];
  float mu = s1 * (1.0f/D_);
  float var = s2 * (1.0f/D_) - mu*mu;
  float rs = rsqrtf(var + 1e-5f);
  float4 gv = ((const float4*)g)[t];
  float4 bv = ((const float4*)b)[t];
  union { ushort u[4]; uint2 p; } o;
  o.u[0] = f2bf((v.x-mu)*rs*gv.x + bv.x);
  o.u[1] = f2bf((v.y-mu)*rs*gv.y + bv.y);
  o.u[2] = f2bf((v.z-mu)*rs*gv.z + bv.z);
  o.u[3] = f2bf((v.w-mu)*rs*gv.w + bv.w);
  ((uint2*)(h + (size_t)row*D_))[t] = o.p;
}

// ---------------- final layernorm on compact [2][D] buffer -> fp32 out ----------------
__global__ void k_lnf(const float* __restrict__ xf, const float* __restrict__ g,
                      const float* __restrict__ b, float* __restrict__ out){
  int row = blockIdx.x;            // 0..B_-1
  int t = threadIdx.x;
  float4 v = ((const float4*)(xf + (size_t)row*D_))[t];
  float s1 = v.x+v.y+v.z+v.w;
  float s2 = v.x*v.x+v.y*v.y+v.z*v.z+v.w*v.w;
  #pragma unroll
  for (int o=1;o<64;o<<=1){ s1 += __shfl_xor(s1,o); s2 += __shfl_xor(s2,o); }
  __shared__ float sm[8];
  int w = t>>6;
  if ((t&63)==0){ sm[w]=s1; sm[4+w]=s2; }
  __syncthreads();
  s1 = sm[0]+sm[1]+sm[2]+sm[3];
  s2 = sm[4]+sm[5]+sm[6]+sm[7];
  float mu = s1 * (1.0f/D_);
  float var = s2 * (1.0f/D_) - mu*mu;
  float rs = rsqrtf(var + 1e-5f);
  float4 gv = ((const float4*)g)[t];
  float4 bv = ((const float4*)b)[t];
  float4 y;
  y.x = (v.x-mu)*rs*gv.x + bv.x;
  y.y = (v.y-mu)*rs*gv.y + bv.y;
  y.z = (v.z-mu)*rs*gv.z + bv.z;
  y.w = (v.w-mu)*rs*gv.w + bv.w;
  ((float4*)(out + (size_t)row*D_))[t] = y;
}

// ---------------- GEMM: C[m,n] = sum_k A_bf16[m,k] * B_f32[n,k] (split-K partials) ----
// BM=BN=128, BK=32, 256 threads (4 waves, 2x2), each wave 64x64 via 4x4 MFMA 16x16x32.
// blockIdx.z = mat*kchunks + chunk; chunk writes its partial to C + chunk*coff.
#define LDA 40   // ushort stride: 80B rows -> 16B aligned, ~2-way banks on b128 reads
__global__ __launch_bounds__(256) void k_gemm_bt(
    const ushort* __restrict__ A,
    const float* __restrict__ B0, const float* __restrict__ B1, const float* __restrict__ B2,
    float* __restrict__ C0, float* __restrict__ C1, float* __restrict__ C2,
    int N, int K, int kchunks, int coff){
  const int z = blockIdx.z;
  const int mat = z / kchunks, chunk = z - mat*kchunks;
  const float* B = (mat==0) ? B0 : ((mat==1) ? B1 : B2);
  float* C = ((mat==0) ? C0 : ((mat==1) ? C1 : C2)) + (size_t)chunk * coff;
  const int Kc = K / kchunks;
  const int kbeg = chunk*Kc, kend = kbeg + Kc;
  const int m0 = blockIdx.x*128, n0 = blockIdx.y*128;
  __shared__ ushort As[128*LDA];
  __shared__ ushort Bs[128*LDA];
  const int t = threadIdx.x;
  const int lane = t & 63, w = t >> 6;
  const int wm = (w & 1)*64, wn = (w >> 1)*64;
  const int fr = lane & 15, fk = (lane >> 4)*8;
  const int trow = t >> 1, tcol = (t & 1)*16;
  const ushort* Ag = A + (size_t)(m0 + trow)*K + tcol;
  const float*  Bg = B + (size_t)(n0 + trow)*K + tcol;
  ushort* Asw = &As[trow*LDA + tcol];
  ushort* Bsw = &Bs[trow*LDA + tcol];

  f32x4 acc[4][4];
  #pragma unroll
  for (int i=0;i<4;i++)
    #pragma unroll
    for (int j=0;j<4;j++)
      #pragma unroll
      for (int r=0;r<4;r++) acc[i][j][r] = 0.0f;

  for (int k0 = kbeg; k0 < kend; k0 += 32){
    uint4 a0 = *(const uint4*)(Ag + k0);
    uint4 a1 = *(const uint4*)(Ag + k0 + 8);
    float4 q0 = *(const float4*)(Bg + k0);
    float4 q1 = *(const float4*)(Bg + k0 + 4);
    float4 q2 = *(const float4*)(Bg + k0 + 8);
    float4 q3 = *(const float4*)(Bg + k0 + 12);
    __syncthreads();   // previous iter's frag reads done
    *(uint4*)(Asw)     = a0;
    *(uint4*)(Asw + 8) = a1;
    *(uint4*)(Bsw)     = pack8(q0, q1);
    *(uint4*)(Bsw + 8) = pack8(q2, q3);
    __syncthreads();
    bf16x8 af[4], bfr[4];
    #pragma unroll
    for (int i=0;i<4;i++) af[i]  = *(const bf16x8*)&As[(wm + i*16 + fr)*LDA + fk];
    #pragma unroll
    for (int j=0;j<4;j++) bfr[j] = *(const bf16x8*)&Bs[(wn + j*16 + fr)*LDA + fk];
    #pragma unroll
    for (int i=0;i<4;i++)
      #pragma unroll
      for (int j=0;j<4;j++)
        acc[i][j] = __builtin_amdgcn_mfma_f32_16x16x32_bf16(af[i], bfr[j], acc[i][j], 0, 0, 0);
  }
  // epilogue: C/D layout col=lane&15, row=(lane>>4)*4+reg
  #pragma unroll
  for (int i=0;i<4;i++){
    int row = m0 + wm + i*16 + (lane >> 4)*4;
    #pragma unroll
    for (int j=0;j<4;j++){
      int col = n0 + wn + j*16 + (lane & 15);
      float* cp = C + (size_t)row*N + col;
      #pragma unroll
      for (int r=0;r<4;r++) cp[(size_t)r*N] = acc[i][j][r];
    }
  }
}

// ---------------- dual-B W1/W3 GEMM + fused SiLU -> bf16 pb ----------------
__global__ __launch_bounds__(256) void k_gemm_w13(
    const ushort* __restrict__ A,       // h bf16 [B*S][D]
    const float* __restrict__ W1, const float* __restrict__ W3,
    ushort* __restrict__ P){            // pb bf16 [B*S][F]
  const int m0 = blockIdx.x*128, n0 = blockIdx.y*64;
  __shared__ ushort As [128*LDA];
  __shared__ ushort B1s[64*LDA];
  __shared__ ushort B3s[64*LDA];
  const int t = threadIdx.x;
  const int lane = t & 63, w = t >> 6;
  const int wm = (w & 1)*64, wn = (w >> 1)*32;
  const int fr = lane & 15, fk = (lane >> 4)*8;
  const int trA = t >> 1, tcA = (t & 1)*16;
  const int trB = t >> 2, tcB = (t & 3)*8;
  const ushort* Ag  = A  + (size_t)(m0 + trA)*D_ + tcA;
  const float*  B1g = W1 + (size_t)(n0 + trB)*D_ + tcB;
  const float*  B3g = W3 + (size_t)(n0 + trB)*D_ + tcB;
  ushort* Asw = &As [trA*LDA + tcA];
  ushort* B1w = &B1s[trB*LDA + tcB];
  ushort* B3w = &B3s[trB*LDA + tcB];

  f32x4 a1[4][2], a3[4][2];
  #pragma unroll
  for (int i=0;i<4;i++)
    #pragma unroll
    for (int j=0;j<2;j++)
      #pragma unroll
      for (int r=0;r<4;r++){ a1[i][j][r]=0.f; a3[i][j][r]=0.f; }

  for (int k0 = 0; k0 < D_; k0 += 32){
    uint4 av0 = *(const uint4*)(Ag + k0);
    uint4 av1 = *(const uint4*)(Ag + k0 + 8);
    float4 p0 = *(const float4*)(B1g + k0);
    float4 p1 = *(const float4*)(B1g + k0 + 4);
    float4 r0 = *(const float4*)(B3g + k0);
    float4 r1 = *(const float4*)(B3g + k0 + 4);
    __syncthreads();
    *(uint4*)(Asw)     = av0;
    *(uint4*)(Asw + 8) = av1;
    *(uint4*)(B1w)     = pack8(p0, p1);
    *(uint4*)(B3w)     = pack8(r0, r1);
    __syncthreads();
    bf16x8 af[4], b1f[2], b3f[2];
    #pragma unroll
    for (int i=0;i<4;i++) af[i]  = *(const bf16x8*)&As [(wm + i*16 + fr)*LDA + fk];
    #pragma unroll
    for (int j=0;j<2;j++){
      b1f[j] = *(const bf16x8*)&B1s[(wn + j*16 + fr)*LDA + fk];
      b3f[j] = *(const bf16x8*)&B3s[(wn + j*16 + fr)*LDA + fk];
    }
    #pragma unroll
    for (int i=0;i<4;i++)
      #pragma unroll
      for (int j=0;j<2;j++){
        a1[i][j] = __builtin_amdgcn_mfma_f32_16x16x32_bf16(af[i], b1f[j], a1[i][j], 0, 0, 0);
        a3[i][j] = __builtin_amdgcn_mfma_f32_16x16x32_bf16(af[i], b3f[j], a3[i][j], 0, 0, 0);
      }
  }
  #pragma unroll
  for (int i=0;i<4;i++){
    int row = m0 + wm + i*16 + (lane >> 4)*4;
    #pragma unroll
    for (int j=0;j<2;j++){
      int col = n0 + wn + j*16 + (lane & 15);
      #pragma unroll
      for (int r=0;r<4;r++){
        float u = a1[i][j][r];
        float s = u / (1.f + __expf(-u)) * a3[i][j][r];
        P[(size_t)(row + r)*F_ + col] = f2bf(s);
      }
    }
  }
}

// ---------------- fused prep: sum QKV partials; RoPE(Q,K) -> bf16; V -> V^T bf16 ----
// mode 0: blocks [0,half)=Q rope, [half,2half)=K rope, rest=V transpose
// mode 1 (last layer): blocks [0,half)=K rope, rest=V transpose (no Q)
__global__ void k_prep(const float* __restrict__ q0, const float* __restrict__ q1,
                       const float* __restrict__ kp0, const float* __restrict__ kp1,
                       const float* __restrict__ v0, const float* __restrict__ v1,
                       ushort* __restrict__ qdst, ushort* __restrict__ kdst,
                       ushort* __restrict__ vt, int mode){
  __shared__ float vl[64*68];
  const int half = (B_*S_*D_)/256;   // 8192
  int bx = blockIdx.x;
  int t = threadIdx.x;
  const int nrope = (mode == 0) ? 2*half : half;
  if (bx < nrope){
    const float *src0, *src1; ushort* dst;
    if (mode == 0 && bx < half){ src0 = q0; src1 = q1; dst = qdst; }
    else { src0 = kp0; src1 = kp1; dst = kdst; if (mode == 0) bx -= half; }
    int idx = bx*256 + t;
    int d = idx & 63;
    int s = (idx >> 10) & (S_-1);
    float v = src0[idx] + src1[idx];
    float p = __shfl_xor(v, 32);
    float rot = (d < 32) ? -p : p;
    float inv = expf(-(float)(d & 31) * 0.28782313662f);  // ln(10000)/32
    float sn, cs; sincosf((float)s * inv, &sn, &cs);
    dst[idx] = f2bf(v*cs + rot*sn);
    return;
  }
  bx -= nrope;
  int s0 = (bx & 15)*64, bh = bx >> 4;
  int b = bh >> 4, hh = bh & 15;
  int j = t >> 2, off = (t & 3)*16;
  size_t sidx = ((size_t)(b*S_ + s0 + j))*D_ + hh*64 + off;
  const float* sa = v0 + sidx;
  const float* sb = v1 + sidx;
  #pragma unroll
  for (int q=0; q<4; q++){
    float4 ra = ((const float4*)sa)[q];
    float4 rb = ((const float4*)sb)[q];
    float4 rs; rs.x=ra.x+rb.x; rs.y=ra.y+rb.y; rs.z=ra.z+rb.z; rs.w=ra.w+rb.w;
    *(float4*)&vl[j*68 + off + q*4] = rs;
  }
  __syncthreads();
  int d = t >> 2, so = (t & 3)*16;
  ushort* dst = vt + ((size_t)bh*64 + d)*S_ + s0 + so;
  union { ushort u[8]; uint4 q; } o0, o1;
  #pragma unroll
  for (int jj=0; jj<8; jj++) o0.u[jj] = f2bf(vl[(so + jj)*68 + d]);
  #pragma unroll
  for (int jj=0; jj<8; jj++) o1.u[jj] = f2bf(vl[(so + 8 + jj)*68 + d]);
  *(uint4*)dst       = o0.q;
  *(uint4*)(dst + 8) = o1.q;
}

// ---------------- MFMA flash attention (causal, online softmax) -> bf16 ctx -------
#define LDK 72
__global__ __launch_bounds__(256) void k_flash(
    const ushort* __restrict__ qh, const ushort* __restrict__ kh,
    const ushort* __restrict__ vt, ushort* __restrict__ ctx){
  __shared__ ushort Kl[64*LDK];      // [key][d]
  __shared__ ushort Vl[64*LDK];      // [d][key]
  __shared__ ushort Pl[4][16*LDK];   // per-wave [q][key]
  const int t = threadIdx.x, lane = t & 63, w = t >> 6;
  const int bh = blockIdx.x, b = bh >> 4, hh = bh & 15;
  const int yy = blockIdx.y;
  const int q0 = 64 * ((yy < 8) ? (15 - 2*yy) : (2*yy - 16));
  const int qw = q0 + w*16;
  const int fr = lane & 15, fk = (lane >> 4)*8;
  bf16x8 qf0, qf1;
  {
    const ushort* qp = qh + ((size_t)(b*S_ + qw + fr))*D_ + hh*64;
    qf0 = *(const bf16x8*)(qp + fk);
    qf1 = *(const bf16x8*)(qp + 32 + fk);
  }
  f32x4 o[4];
  float m[4], l[4];
  #pragma unroll
  for (int r=0;r<4;r++){
    m[r] = -1e30f; l[r] = 0.f;
    #pragma unroll
    for (int j=0;j<4;j++) o[j][r] = 0.f;
  }
  const int nch = q0/64 + 1;
  const int sr = t >> 2, soff = (t & 3)*16;
  ushort* Plw = Pl[w];
  const int rbase = qw + (lane >> 4)*4;
  for (int c=0; c<nch; c++){
    const int k0 = c*64;
    __syncthreads();
    {
      const uint4* ks = (const uint4*)(kh + ((size_t)(b*S_ + k0 + sr))*D_ + hh*64 + soff);
      uint4 ka = ks[0], kb2 = ks[1];
      const uint4* vs = (const uint4*)(vt + ((size_t)(bh*64 + sr))*S_ + k0 + soff);
      uint4 va = vs[0], vb2 = vs[1];
      *(uint4*)&Kl[sr*LDK + soff]     = ka;
      *(uint4*)&Kl[sr*LDK + soff + 8] = kb2;
      *(uint4*)&Vl[sr*LDK + soff]     = va;
      *(uint4*)&Vl[sr*LDK + soff + 8] = vb2;
    }
    __syncthreads();
    f32x4 sc[4];
    #pragma unroll
    for (int j=0;j<4;j++){
      bf16x8 kf0 = *(const bf16x8*)&Kl[(j*16 + fr)*LDK + fk];
      bf16x8 kf1 = *(const bf16x8*)&Kl[(j*16 + fr)*LDK + 32 + fk];
      f32x4 z; z[0]=0.f; z[1]=0.f; z[2]=0.f; z[3]=0.f;
      z = __builtin_amdgcn_mfma_f32_16x16x32_bf16(qf0, kf0, z, 0, 0, 0);
      sc[j] = __builtin_amdgcn_mfma_f32_16x16x32_bf16(qf1, kf1, z, 0, 0, 0);
    }
    #pragma unroll
    for (int r=0;r<4;r++){
      const int qrow = rbase + r;
      float mc = -1e30f;
      #pragma unroll
      for (int j=0;j<4;j++){
        float sv = (k0 + j*16 + fr <= qrow) ? sc[j][r]*0.125f : -1e30f;
        sc[j][r] = sv;
        mc = fmaxf(mc, sv);
      }
      #pragma unroll
      for (int ofs=1; ofs<16; ofs<<=1) mc = fmaxf(mc, __shfl_xor(mc, ofs));
      float mn = fmaxf(m[r], mc);
      float al = __expf(m[r] - mn);
      float sum = 0.f;
      #pragma unroll
      for (int j=0;j<4;j++){
        float p = __expf(sc[j][r] - mn);
        sum += p;
        Plw[(((lane >> 4)*4) + r)*LDK + j*16 + fr] = f2bf(p);
      }
      #pragma unroll
      for (int ofs=1; ofs<16; ofs<<=1) sum += __shfl_xor(sum, ofs);
      l[r] = l[r]*al + sum;
      m[r] = mn;
      #pragma unroll
      for (int j=0;j<4;j++) o[j][r] *= al;
    }
    bf16x8 pa0 = *(const bf16x8*)&Plw[fr*LDK + fk];
    bf16x8 pa1 = *(const bf16x8*)&Plw[fr*LDK + 32 + fk];
    #pragma unroll
    for (int j=0;j<4;j++){
      bf16x8 vf0 = *(const bf16x8*)&Vl[(j*16 + fr)*LDK + fk];
      bf16x8 vf1 = *(const bf16x8*)&Vl[(j*16 + fr)*LDK + 32 + fk];
      o[j] = __builtin_amdgcn_mfma_f32_16x16x32_bf16(pa0, vf0, o[j], 0, 0, 0);
      o[j] = __builtin_amdgcn_mfma_f32_16x16x32_bf16(pa1, vf1, o[j], 0, 0, 0);
    }
  }
  #pragma unroll
  for (int r=0;r<4;r++){
    float rl = 1.0f / l[r];
    ushort* cp = ctx + ((size_t)(b*S_ + rbase + r))*D_ + hh*64 + fr;
    #pragma unroll
    for (int j=0;j<4;j++) cp[j*16] = f2bf(o[j][r] * rl);
  }
}

// ---------------- 2-row skinny GEMM: C[2][N] = (add?) + A2_bf16 . B_f32^T ----------
__global__ __launch_bounds__(256) void k_row1(
    const ushort* __restrict__ A0, const ushort* __restrict__ A1,
    const float* __restrict__ B, int K,
    const float* __restrict__ add0, const float* __restrict__ add1,
    float* __restrict__ C, int N){
  __shared__ ushort As[2*4096];
  const int t = threadIdx.x;
  const int nv = 2*K/8;
  for (int i = t; i < nv; i += 256){
    int row = (i*8 >= K) ? 1 : 0;
    int off = i*8 - row*K;
    ((uint4*)As)[i] = *(const uint4*)((row ? A1 : A0) + off);
  }
  __syncthreads();
  const int col = blockIdx.x*16 + (t >> 4);
  const int p = t & 15;
  const float* Bp = B + (size_t)col*K;
  float acc0 = 0.f, acc1 = 0.f;
  for (int i = 0; i < K/64; i++){
    int k = p*4 + i*64;
    float4 bv = *(const float4*)(Bp + k);
    ushort4 u0 = *(const ushort4*)&As[k];
    ushort4 u1 = *(const ushort4*)&As[K + k];
    acc0 += bv.x*bf2f(u0.x) + bv.y*bf2f(u0.y) + bv.z*bf2f(u0.z) + bv.w*bf2f(u0.w);
    acc1 += bv.x*bf2f(u1.x) + bv.y*bf2f(u1.y) + bv.z*bf2f(u1.z) + bv.w*bf2f(u1.w);
  }
  #pragma unroll
  for (int ofs=1; ofs<16; ofs<<=1){ acc0 += __shfl_xor(acc0, ofs); acc1 += __shfl_xor(acc1, ofs); }
  if (p == 0){
    C[col]     = (add0 ? add0[col] : 0.f) + acc0;
    C[N + col] = (add1 ? add1[col] : 0.f) + acc1;
  }
}

// ---------------- 2-row dual-B GEMM + SiLU: pl[2][F] = silu(h2.w1)*(h2.w3) ----------
__global__ __launch_bounds__(256) void k_row13(
    const ushort* __restrict__ H2,      // [2][D] bf16 compact
    const float* __restrict__ W1, const float* __restrict__ W3,
    ushort* __restrict__ P){            // [2][F]
  __shared__ ushort As[2*1024];
  const int t = threadIdx.x;
  ((uint4*)As)[t] = *(const uint4*)(H2 + t*8);
  __syncthreads();
  const int col = blockIdx.x*16 + (t >> 4);
  const int p = t & 15;
  const float* b1 = W1 + (size_t)col*D_;
  const float* b3 = W3 + (size_t)col*D_;
  float u10=0.f, u11=0.f, u30=0.f, u31=0.f;
  for (int i = 0; i < D_/64; i++){
    int k = p*4 + i*64;
    float4 v1 = *(const float4*)(b1 + k);
    float4 v3 = *(const float4*)(b3 + k);
    ushort4 a0 = *(const ushort4*)&As[k];
    ushort4 a1 = *(const ushort4*)&As[D_ + k];
    float f00=bf2f(a0.x), f01=bf2f(a0.y), f02=bf2f(a0.z), f03=bf2f(a0.w);
    float f10=bf2f(a1.x), f11=bf2f(a1.y), f12=bf2f(a1.z), f13=bf2f(a1.w);
    u10 += v1.x*f00 + v1.y*f01 + v1.z*f02 + v1.w*f03;
    u11 += v1.x*f10 + v1.y*f11 + v1.z*f12 + v1.w*f13;
    u30 += v3.x*f00 + v3.y*f01 + v3.z*f02 + v3.w*f03;
    u31 += v3.x*f10 + v3.y*f11 + v3.z*f12 + v3.w*f13;
  }
  #pragma unroll
  for (int ofs=1; ofs<16; ofs<<=1){
    u10 += __shfl_xor(u10, ofs); u11 += __shfl_xor(u11, ofs);
    u30 += __shfl_xor(u30, ofs); u31 += __shfl_xor(u31, ofs);
  }
  if (p == 0){
    P[col]      = f2bf(u10 / (1.f + __expf(-u10)) * u30);
    P[F_ + col] = f2bf(u11 / (1.f + __expf(-u11)) * u31);
  }
}

// ---------------- decode attention: 1 query (last token) per (b,h) ----------------
__global__ __launch_bounds__(256) void k_dec(
    const float* __restrict__ q2,       // [2][D] pre-RoPE fp32
    const ushort* __restrict__ kh,      // [b,s,h,d] bf16 (RoPE'd)
    const ushort* __restrict__ vt,      // [bh][d][S] bf16
    ushort* __restrict__ c2){           // [2][D] bf16 ctx
  __shared__ float qs[64];
  __shared__ float ps[S_];
  __shared__ float red[8];
  const int t = threadIdx.x, lane = t & 63, w = t >> 6;
  const int bh = blockIdx.x, b = bh >> 4, hh = bh & 15;
  if (t < 64){
    int d = t;
    float v = q2[b*D_ + hh*64 + d];
    float pr = q2[b*D_ + hh*64 + (d ^ 32)];
    float rot = (d < 32) ? -pr : pr;
    float inv = expf(-(float)(d & 31) * 0.28782313662f);
    float sn, cs; sincosf((float)(S_-1) * inv, &sn, &cs);
    qs[d] = v*cs + rot*sn;
  }
  __syncthreads();
  float sc[4];
  #pragma unroll
  for (int j=0;j<4;j++){
    int key = t + j*256;
    const uint4* kp = (const uint4*)(kh + ((size_t)(b*S_ + key))*D_ + hh*64);
    float acc = 0.f;
    #pragma unroll
    for (int i=0;i<8;i++){
      uint4 kv = kp[i];
      const ushort* ku = (const ushort*)&kv;
      #pragma unroll
      for (int jj=0;jj<8;jj++) acc += qs[i*8+jj] * bf2f(ku[jj]);
    }
    sc[j] = acc * 0.125f;
  }
  float mx = fmaxf(fmaxf(sc[0],sc[1]), fmaxf(sc[2],sc[3]));
  #pragma unroll
  for (int ofs=1; ofs<64; ofs<<=1) mx = fmaxf(mx, __shfl_xor(mx, ofs));
  if (lane == 0) red[w] = mx;
  __syncthreads();
  mx = fmaxf(fmaxf(red[0],red[1]), fmaxf(red[2],red[3]));
  float ls = 0.f;
  #pragma unroll
  for (int j=0;j<4;j++){
    float pv = __expf(sc[j] - mx);
    ps[t + j*256] = pv;
    ls += pv;
  }
  #pragma unroll
  for (int ofs=1; ofs<64; ofs<<=1) ls += __shfl_xor(ls, ofs);
  if (lane == 0) red[4 + w] = ls;
  __syncthreads();
  const float L = red[4]+red[5]+red[6]+red[7];
  const int d = t >> 2, part = t & 3;
  const uint4* vp = (const uint4*)(vt + ((size_t)(bh*64 + d))*S_ + part*256);
  float acc = 0.f;
  for (int i=0;i<32;i++){
    uint4 vv = vp[i];
    const ushort* vu = (const ushort*)&vv;
    #pragma unroll
    for (int jj=0;jj<8;jj++) acc += ps[part*256 + i*8 + jj] * bf2f(vu[jj]);
  }
  acc += __shfl_xor(acc, 1);
  acc += __shfl_xor(acc, 2);
  if (part == 0) c2[b*D_ + hh*64 + d] = f2bf(acc / L);
}

extern "C" void kernel_launch(void* const* d_in, const int* in_sizes, int n_in,
                              void* d_out, int out_size, void* d_ws, size_t ws_size,
                              hipStream_t stream) {
  const int*   ids  = (const int*)  d_in[0];
  const float* tok  = (const float*)d_in[1];
  const float* pos  = (const float*)d_in[2];
  const float* wq   = (const float*)d_in[3];
  const float* wk   = (const float*)d_in[4];
  const float* wv   = (const float*)d_in[5];
  const float* wo   = (const float*)d_in[6];
  const float* w1   = (const float*)d_in[7];
  const float* w2   = (const float*)d_in[8];
  const float* w3   = (const float*)d_in[9];
  const float* ln1g = (const float*)d_in[10];
  const float* ln1b = (const float*)d_in[11];
  const float* ln2g = (const float*)d_in[12];
  const float* ln2b = (const float*)d_in[13];
  const float* lnfg = (const float*)d_in[14];
  const float* lnfb = (const float*)d_in[15];

  char* wsb = (char*)d_ws;
  float*  x  = (float*) (wsb);                               // 8 MB
  ushort* h  = (ushort*)(wsb + (size_t)8*1024*1024);         // 4 MB bf16 LN output
  ushort* vt = (ushort*)(wsb + (size_t)12*1024*1024);        // 4 MB bf16 V^T
  ushort* qh = (ushort*)(wsb + (size_t)16*1024*1024);        // 4 MB bf16 Q (post-RoPE)
  ushort* kh = (ushort*)(wsb + (size_t)20*1024*1024);        // 4 MB bf16 K (post-RoPE)
  ushort* cx = (ushort*)(wsb + (size_t)24*1024*1024);        // 4 MB bf16 ctx
  // last-layer skinny buffers (28 MB region)
  float*  q2 = (float*) (wsb + (size_t)28*1024*1024);        // [2][1024] fp32
  ushort* c2 = (ushort*)(wsb + (size_t)28*1024*1024 + 8192); // [2][1024] bf16
  float*  xl = (float*) (wsb + (size_t)28*1024*1024 + 16384);// [2][1024] fp32
  ushort* h2 = (ushort*)(wsb + (size_t)28*1024*1024 + 24576);// [2][1024] bf16
  ushort* pl = (ushort*)(wsb + (size_t)28*1024*1024 + 32768);// [2][4096] bf16
  float*  xf = (float*) (wsb + (size_t)28*1024*1024 + 49152);// [2][1024] fp32
  float*  qp = (float*) (wsb + (size_t)48*1024*1024);        // partials region: 64 MB
  ushort* pb = (ushort*)(wsb + (size_t)112*1024*1024);       // 16 MB -> total 128 MB

  // partials region reuse (all sequentially dead/live within a layer):
  //   QKV: 2 chunks x {q,k,v} x 8 MB at [48,96)
  //   wo : 4 chunks x 8 MB at [48,80)
  //   W2 : 8 chunks x 8 MB at [48,112)
  const int QKV_COFF = 8*1024*1024;                 // floats (32 MB stride)
  const int RED_COFF = 2*1024*1024;                 // floats (8 MB stride)
  float* kp = qp + 2*1024*1024;                     // k partials
  float* vp = qp + 4*1024*1024;                     // v partials

  k_embed<<<B_*S_, 256, 0, stream>>>(ids, tok, pos, x);
  k_ln<<<B_*S_, 256, 0, stream>>>(x, ln1g, ln1b, h);   // h = LN1(layer 0)

  for (int l = 0; l < L_-1; l++){
    size_t od = (size_t)l*D_*D_;
    size_t fd = (size_t)l*F_*D_;
    // fused Q/K/V, split-K x2 -> 768 blocks, partials (no atomics)
    k_gemm_bt<<<dim3(16, 8, 6), 256, 0, stream>>>(h, wq + od, wk + od, wv + od,
                                                  qp, kp, vp, D_, D_, 2, QKV_COFF);
    k_prep<<<2*(B_*S_*D_)/256 + (S_/64)*B_*H_, 256, 0, stream>>>(
        qp, qp + QKV_COFF, kp, kp + QKV_COFF, vp, vp + QKV_COFF, qh, kh, vt, 0);
    k_flash<<<dim3(B_*H_, S_/64), 256, 0, stream>>>(qh, kh, vt, cx);
    // wo projection split-K x4 -> 512 blocks, partials; then x += sum, h = LN2(x)
    k_gemm_bt<<<dim3(16, 8, 4), 256, 0, stream>>>(cx, wo + od, nullptr, nullptr,
                                                  qp, nullptr, nullptr, D_, D_, 4, RED_COFF);
    k_red_ln<<<B_*S_, 256, 0, stream>>>(qp, 4, RED_COFF, x, ln2g + l*D_, ln2b + l*D_, h);
    // dual-B W1/W3 + fused SiLU -> pb (bf16), 1024 blocks
    k_gemm_w13<<<dim3(16, 64), 256, 0, stream>>>(h, w1 + fd, w3 + fd, pb);
    // W2 split-K x8 -> 1024 blocks, partials; then x += sum, h = LN1(next layer)
    k_gemm_bt<<<dim3(16, 8, 8), 256, 0, stream>>>(pb, w2 + fd, nullptr, nullptr,
                                                  qp, nullptr, nullptr, D_, F_, 8, RED_COFF);
    k_red_ln<<<B_*S_, 256, 0, stream>>>(qp, 8, RED_COFF, x, ln1g + (l+1)*D_, ln1b + (l+1)*D_, h);
  }

  {
    // last layer: only the final token per batch matters downstream. h = LN1[5](x).
    int l = L_-1;
    size_t od = (size_t)l*D_*D_;
    size_t fd = (size_t)l*F_*D_;
    // K,V projections (all rows), split-K x2 -> 512 blocks
    k_gemm_bt<<<dim3(16, 8, 4), 256, 0, stream>>>(h, wk + od, wv + od, nullptr,
                                                  kp, vp, nullptr, D_, D_, 2, QKV_COFF);
    // K rope + V transpose only
    k_prep<<<(B_*S_*D_)/256 + (S_/64)*B_*H_, 256, 0, stream>>>(
        nullptr, nullptr, kp, kp + QKV_COFF, vp, vp + QKV_COFF, qh, kh, vt, 1);
    // Q for the 2 last rows (pre-rope; rope applied inside k_dec)
    k_row1<<<64, 256, 0, stream>>>(h + (size_t)(S_-1)*D_, h + (size_t)(B_*S_-1)*D_,
                                   wq + od, D_, nullptr, nullptr, q2, D_);
    k_dec<<<B_*H_, 256, 0, stream>>>(q2, kh, vt, c2);
    // wo projection + residual for 2 rows -> xl
    k_row1<<<64, 256, 0, stream>>>(c2, c2 + D_, wo + od, D_,
                                   x + (size_t)(S_-1)*D_, x + (size_t)(B_*S_-1)*D_, xl, D_);
    k_ln<<<2, 256, 0, stream>>>(xl, ln2g + l*D_, ln2b + l*D_, h2);
    k_row13<<<F_/16, 256, 0, stream>>>(h2, w1 + fd, w3 + fd, pl);
    k_row1<<<64, 256, 0, stream>>>(pl, pl + F_, w2 + fd, F_, xl, xl + D_, xf, D_);
  }

  k_lnf<<<B_, 256, 0, stream>>>(xf, lnfg, lnfb, (float*)d_out);
}